// Round 14
// baseline (918.326 us; speedup 1.0000x reference)
//
#include <hip/hip_runtime.h>
#include <hip/hip_bf16.h>

#define N_NODES 51200
#define N_EDGES 300000
#define NFULL   351200   // E + N
#define GRAPHS  512
#define NPGRAPH 100
#define FATOM   64
#define FEDGE   8
#define HDIM    256
#define NHEADS  8
#define DHEAD   32
#define LAYERS  4
#define TASKS   5
#define BN_SLOTS 16
#define SCAN_BLOCKS 50   // 50 * 1024 = 51200

typedef unsigned short u16;
typedef __attribute__((ext_vector_type(8))) short bf16x8;
typedef __attribute__((ext_vector_type(4))) float f32x4;

__device__ __forceinline__ float b2f(u16 u) {
    return __uint_as_float(((unsigned)u) << 16);
}
__device__ __forceinline__ u16 f2bf(float f) {
    unsigned u = __float_as_uint(f);
    unsigned r = u + 0x7fffu + ((u >> 16) & 1u);   // round-to-nearest-even
    return (u16)(r >> 16);
}

// ---------------------------------------------------------------------------
// fp32 -> bf16 flat convert
// ---------------------------------------------------------------------------
__global__ __launch_bounds__(256)
void convert_kernel(const float* __restrict__ in, u16* __restrict__ out, int n) {
    int i = blockIdx.x * 256 + threadIdx.x;
    if (i < n) out[i] = f2bf(in[i]);
}

// fp32 [R][C] -> bf16 [C][R]
__global__ __launch_bounds__(256)
void convert_t_kernel(const float* __restrict__ in, u16* __restrict__ out, int R, int C) {
    int idx = blockIdx.x * 256 + threadIdx.x;
    if (idx >= R * C) return;
    int c = idx / R, r = idx % R;
    out[idx] = f2bf(in[(size_t)r * C + c]);
}

// 4 layers of [256][256] transposed in one launch
__global__ __launch_bounds__(256)
void convert_t4_kernel(const float* __restrict__ in, u16* __restrict__ out) {
    int idx = blockIdx.x * 256 + threadIdx.x;   // 4*65536
    int li = idx >> 16, rem = idx & 65535;
    int c = rem >> 8, r = rem & 255;
    out[idx] = f2bf(in[(size_t)li * 65536 + r * 256 + c]);
}

// ---------------------------------------------------------------------------
// MFMA bf16 GEMM (round-11 verified): BM=BN=128, BK=64, 4 waves 2x2,
// XCD chunk swizzle, LDS epilogue -> coalesced 16B stores.
// ---------------------------------------------------------------------------
template<bool BIAS, bool RELU>
__global__ __launch_bounds__(256, 2)
void gemm_mfma_kernel(const u16* __restrict__ A, const u16* __restrict__ Bt,
                      const float* __restrict__ bias, u16* __restrict__ C,
                      int M, int K, int N) {
    __shared__ u16 smem[136 * 128];
    u16* As = smem;                          // [128][64]
    u16* Bs = smem + 128 * 64;               // [128][64]
    const int t = threadIdx.x;
    const int lane = t & 63;
    const int w = t >> 6;
    const int wr = w >> 1, wc = w & 1;

    const int nwg = (int)gridDim.x;
    const int bid = (int)blockIdx.x;
    const int q = nwg >> 3, r = nwg & 7;
    const int xcd = bid & 7, idx0 = bid >> 3;
    const int wgid = (xcd < r) ? xcd * (q + 1) + idx0
                               : r * (q + 1) + (xcd - r) * q + idx0;
    const int nx = N >> 7;
    const int bn = (wgid % nx) * 128;
    const int bm = (wgid / nx) * 128;

    f32x4 acc[4][4] = {};

    for (int kt = 0; kt < K; kt += 64) {
        uint4 ra[4], rb[4];
#pragma unroll
        for (int i = 0; i < 4; ++i) {
            int idx = i * 256 + t;
            int row = idx >> 3, ch = idx & 7;
            ra[i] = *(const uint4*)(A + (size_t)(bm + row) * K + kt + ch * 8);
            rb[i] = *(const uint4*)(Bt + (size_t)(bn + row) * K + kt + ch * 8);
        }
        __syncthreads();
#pragma unroll
        for (int i = 0; i < 4; ++i) {
            int idx = i * 256 + t;
            int row = idx >> 3, ch = idx & 7;
            int sw = ch ^ (row & 7);
            *(uint4*)((char*)As + row * 128 + sw * 16) = ra[i];
            *(uint4*)((char*)Bs + row * 128 + sw * 16) = rb[i];
        }
        __syncthreads();
#pragma unroll
        for (int kk = 0; kk < 2; ++kk) {
            bf16x8 af[4], bf[4];
#pragma unroll
            for (int m = 0; m < 4; ++m) {
                int rr = wr * 64 + m * 16 + (lane & 15);
                int ch = kk * 4 + (lane >> 4);
                af[m] = *(const bf16x8*)((const char*)As + rr * 128 + ((ch ^ (rr & 7)) << 4));
            }
#pragma unroll
            for (int n = 0; n < 4; ++n) {
                int rr = wc * 64 + n * 16 + (lane & 15);
                int ch = kk * 4 + (lane >> 4);
                bf[n] = *(const bf16x8*)((const char*)Bs + rr * 128 + ((ch ^ (rr & 7)) << 4));
            }
#pragma unroll
            for (int m = 0; m < 4; ++m)
#pragma unroll
                for (int n = 0; n < 4; ++n)
                    acc[m][n] = __builtin_amdgcn_mfma_f32_16x16x32_bf16(
                        af[m], bf[n], acc[m][n], 0, 0, 0);
        }
    }
    __syncthreads();
#pragma unroll
    for (int m = 0; m < 4; ++m)
#pragma unroll
        for (int n = 0; n < 4; ++n) {
            int coll = wc * 64 + n * 16 + (lane & 15);
            float bv = BIAS ? bias[bn + coll] : 0.f;
#pragma unroll
            for (int j = 0; j < 4; ++j) {
                float v = acc[m][n][j] + bv;
                if (RELU) v = fmaxf(v, 0.f);
                int rowl = wr * 64 + m * 16 + (lane >> 4) * 4 + j;
                smem[rowl * 136 + coll] = f2bf(v);
            }
        }
    __syncthreads();
#pragma unroll
    for (int p = 0; p < 8; ++p) {
        int rowl = p * 16 + (t >> 4);
        uint4 v = *(const uint4*)(smem + rowl * 136 + (t & 15) * 8);
        *(uint4*)(C + (size_t)(bm + rowl) * N + bn + (t & 15) * 8) = v;
    }
}

// ---------------------------------------------------------------------------
// Degree histogram (int atomics)
// ---------------------------------------------------------------------------
__global__ __launch_bounds__(256)
void edge_hist_kernel(const int* __restrict__ dst, int* __restrict__ deg) {
    int e = blockIdx.x * 256 + threadIdx.x;
    if (e >= N_EDGES) return;
    atomicAdd(&deg[dst[e]], 1);
}

// ---------------------------------------------------------------------------
// Three-stage exclusive scan of (deg[i]+1) -> row_ptr[0..N]
// ---------------------------------------------------------------------------
__global__ __launch_bounds__(1024)
void scan1_kernel(const int* __restrict__ deg, int* __restrict__ row_ptr,
                  int* __restrict__ bsum) {
    __shared__ int buf[1024];
    const int b = blockIdx.x, t = threadIdx.x;
    const int i = b * 1024 + t;
    int v = deg[i] + 1;
    buf[t] = v;
    __syncthreads();
    for (int off = 1; off < 1024; off <<= 1) {
        int x = (t >= off) ? buf[t - off] : 0;
        __syncthreads();
        buf[t] += x;
        __syncthreads();
    }
    row_ptr[i] = buf[t] - v;               // exclusive within block
    if (t == 1023) bsum[b] = buf[t];
}

__global__ __launch_bounds__(64)
void scan2_kernel(int* __restrict__ bsum, int* __restrict__ row_ptr) {
    int t = threadIdx.x;                   // one wave
    int orig = (t < SCAN_BLOCKS) ? bsum[t] : 0;
    int v = orig;
    for (int off = 1; off < 64; off <<= 1) {
        int x = __shfl_up(v, off);
        if (t >= off) v += x;
    }
    if (t < SCAN_BLOCKS) bsum[t] = v - orig;   // exclusive block offset
    if (t == SCAN_BLOCKS - 1) row_ptr[N_NODES] = v;
}

__global__ __launch_bounds__(256)
void scan3_kernel(int* __restrict__ row_ptr, const int* __restrict__ bsum) {
    int i = blockIdx.x * 256 + threadIdx.x;
    if (i >= N_NODES) return;
    row_ptr[i] += bsum[i >> 10];
}

__global__ __launch_bounds__(256)
void selfloop_init_kernel(const int* __restrict__ row_ptr, int* __restrict__ cursor,
                          int* __restrict__ col_src, int* __restrict__ col_eid) {
    int n = blockIdx.x * 256 + threadIdx.x;
    if (n >= N_NODES) return;
    cursor[n] = row_ptr[n];
    int pos = row_ptr[n + 1] - 1;
    col_src[pos] = n;
    col_eid[pos] = N_EDGES + n;
}

__global__ __launch_bounds__(256)
void scatter_kernel(const int* __restrict__ src, const int* __restrict__ dst,
                    int* __restrict__ cursor, int* __restrict__ col_src,
                    int* __restrict__ col_eid) {
    int e = blockIdx.x * 256 + threadIdx.x;
    if (e >= N_EDGES) return;
    int d = dst[e];
    int pos = atomicAdd(&cursor[d], 1);
    col_src[pos] = src[e];
    col_eid[pos] = e;
}

// ---------------------------------------------------------------------------
// P_e[li][k][nh] = sum_d lin_edge_w[li][k][nh*32+d] * att_edge[li][nh][d]
// ---------------------------------------------------------------------------
__global__ __launch_bounds__(256)
void proj_pe_kernel(const float* __restrict__ lin_edge_w, const float* __restrict__ att_edge,
                    float* __restrict__ P_e) {
    int idx = blockIdx.x * 256 + threadIdx.x;   // 4*256*8 = 8192
    int li = idx >> 11;
    int rem = idx & 2047;
    int k = rem >> 3, nh = rem & 7;
    const float* w = lin_edge_w + (size_t)li * HDIM * HDIM + (size_t)k * HDIM + nh * DHEAD;
    const float* a = att_edge + li * HDIM + nh * DHEAD;
    float s = 0.f;
#pragma unroll
    for (int d = 0; d < DHEAD; ++d) s += w[d] * a[d];
    P_e[idx] = s;
}

// Qm[li][f][nh] = sum_k edge_w[f][k] * P_e[li][k][nh];  c0[li][nh] = edge_b @ P_e
__global__ __launch_bounds__(256)
void proj_q_kernel(const float* __restrict__ edge_w, const float* __restrict__ edge_b,
                   const float* __restrict__ P_e, float* __restrict__ Qm,
                   float* __restrict__ c0m) {
    int t = threadIdx.x;          // 256 = 4*8*8
    int li = t >> 6, f = (t >> 3) & 7, nh = t & 7;
    const float* pe = P_e + li * 2048;
    float q = 0.f;
    for (int k = 0; k < HDIM; ++k) q += edge_w[f * HDIM + k] * pe[k * 8 + nh];
    Qm[t] = q;
    if (t < 32) {
        int li2 = t >> 3, nh2 = t & 7;
        const float* pe2 = P_e + li2 * 2048;
        float c = 0.f;
        for (int k = 0; k < HDIM; ++k) c += edge_b[k] * pe2[k * 8 + nh2];
        c0m[t] = c;
    }
}

// a_e for real edges: [E,32] bf16 ; 8 edges x 32 outputs per block
__global__ __launch_bounds__(256)
void ae_real_kernel(const float* __restrict__ edge_attr, const float* __restrict__ Qm,
                    const float* __restrict__ c0m, u16* __restrict__ a_e_all) {
    __shared__ float ea_s[8][8];
    __shared__ float Qs[256];
    __shared__ float c0s[32];
    const int t = threadIdx.x;
    const int e0 = blockIdx.x * 8;
    if (t < 64) ea_s[t >> 3][t & 7] = edge_attr[(size_t)e0 * 8 + t];
    Qs[t] = Qm[t];
    if (t < 32) c0s[t] = c0m[t];
    __syncthreads();
    int el = t >> 5, o = t & 31;
    int li = o >> 3, nh = o & 7;
    float v = c0s[o];
#pragma unroll
    for (int f = 0; f < 8; ++f) v += ea_s[el][f] * Qs[li * 64 + f * 8 + nh];
    a_e_all[(size_t)(e0 + el) * 32 + o] = f2bf(v);
}

// a_e for self loops (rows E..E+N-1): per-node edge-attr sums via CSR walk
__global__ __launch_bounds__(256)
void ae_self_kernel(const float* __restrict__ edge_attr, const int* __restrict__ row_ptr,
                    const int* __restrict__ col_eid, const float* __restrict__ Qm,
                    const float* __restrict__ c0m, u16* __restrict__ a_e_all) {
    __shared__ float ea_s[8][8];
    __shared__ int deg_s[8];
    __shared__ float Qs[256];
    __shared__ float c0s[32];
    const int t = threadIdx.x;
    const int n0 = blockIdx.x * 8;
    Qs[t] = Qm[t];
    if (t < 32) c0s[t] = c0m[t];
    if (t < 64) {
        int el = t >> 3, f = t & 7;
        int n = n0 + el;
        int s = row_ptr[n], e = row_ptr[n + 1] - 1;   // exclude self-loop slot
        float acc = 0.f;
        for (int p = s; p < e; ++p)
            acc += edge_attr[(size_t)col_eid[p] * FEDGE + f];
        ea_s[el][f] = acc;
        if (f == 0) deg_s[el] = e - s;
    }
    __syncthreads();
    int el = t >> 5, o = t & 31;
    int li = o >> 3, nh = o & 7;
    int dg = deg_s[el];
    float v = 0.f;
    if (dg > 0) {
        float invd = 1.f / (float)dg;
        v = c0s[o];
#pragma unroll
        for (int f = 0; f < 8; ++f) v += ea_s[el][f] * invd * Qs[li * 64 + f * 8 + nh];
    }
    a_e_all[(size_t)(N_EDGES + n0 + el) * 32 + o] = f2bf(v);
}

// ---------------------------------------------------------------------------
// a_src / a_dst from xs(bf16 ws): one wave per node
// ---------------------------------------------------------------------------
__global__ __launch_bounds__(256)
void gat_asd_kernel(const u16* __restrict__ xs, const float* __restrict__ att_src_l,
                    const float* __restrict__ att_dst_l, float* __restrict__ a_src,
                    float* __restrict__ a_dst) {
    int node = (blockIdx.x << 2) + (threadIdx.x >> 6);
    int lane = threadIdx.x & 63;
    int c = lane << 2;
    ushort4 x4 = *(const ushort4*)(xs + (size_t)node * HDIM + c);
    float4 as4 = *(const float4*)(att_src_l + c);
    float4 ad4 = *(const float4*)(att_dst_l + c);
    float x0 = b2f(x4.x), x1 = b2f(x4.y), x2 = b2f(x4.z), x3 = b2f(x4.w);
    float vs = x0 * as4.x + x1 * as4.y + x2 * as4.z + x3 * as4.w;
    float vd = x0 * ad4.x + x1 * ad4.y + x2 * ad4.z + x3 * ad4.w;
#pragma unroll
    for (int off = 4; off >= 1; off >>= 1) {
        vs += __shfl_down(vs, off, 8);
        vd += __shfl_down(vd, off, 8);
    }
    if ((lane & 7) == 0) {
        a_src[node * 8 + (lane >> 3)] = vs;
        a_dst[node * 8 + (lane >> 3)] = vd;
    }
}

// ---------------------------------------------------------------------------
// Fused GAT softmax+aggregate: one wave per dst node, unroll-4 edge pipeline
// ---------------------------------------------------------------------------
__global__ __launch_bounds__(256)
void gat_aggregate_kernel(const u16* __restrict__ xs, const float* __restrict__ a_src,
                          const float* __restrict__ a_dst, const u16* __restrict__ a_e_all,
                          const int* __restrict__ row_ptr, const int* __restrict__ col_src,
                          const int* __restrict__ col_eid, const float* __restrict__ bias_l,
                          u16* __restrict__ outb, int li) {
    int n = (blockIdx.x << 2) + (threadIdx.x >> 6);
    int lane = threadIdx.x & 63;
    int c = lane << 2;
    int nh = lane >> 3;
    const int aeo = li * 8 + nh;
    float adst = a_dst[n * 8 + nh];
    int s = row_ptr[n], e = row_ptr[n + 1];
    float4 acc = make_float4(0.f, 0.f, 0.f, 0.f);
    float den = 0.f;
    int p = s;
    for (; p + 4 <= e; p += 4) {
        int s0 = col_src[p],     s1 = col_src[p + 1];
        int s2 = col_src[p + 2], s3 = col_src[p + 3];
        int e0 = col_eid[p],     e1 = col_eid[p + 1];
        int e2 = col_eid[p + 2], e3 = col_eid[p + 3];
        float as0 = a_src[s0 * 8 + nh], as1 = a_src[s1 * 8 + nh];
        float as2 = a_src[s2 * 8 + nh], as3 = a_src[s3 * 8 + nh];
        float ae0 = b2f(a_e_all[(size_t)e0 * 32 + aeo]);
        float ae1 = b2f(a_e_all[(size_t)e1 * 32 + aeo]);
        float ae2 = b2f(a_e_all[(size_t)e2 * 32 + aeo]);
        float ae3 = b2f(a_e_all[(size_t)e3 * 32 + aeo]);
        ushort4 x0 = *(const ushort4*)(xs + (size_t)s0 * HDIM + c);
        ushort4 x1 = *(const ushort4*)(xs + (size_t)s1 * HDIM + c);
        ushort4 x2 = *(const ushort4*)(xs + (size_t)s2 * HDIM + c);
        ushort4 x3 = *(const ushort4*)(xs + (size_t)s3 * HDIM + c);
        float al0 = as0 + adst + ae0; al0 = (al0 > 0.f) ? al0 : 0.2f * al0;
        float al1 = as1 + adst + ae1; al1 = (al1 > 0.f) ? al1 : 0.2f * al1;
        float al2 = as2 + adst + ae2; al2 = (al2 > 0.f) ? al2 : 0.2f * al2;
        float al3 = as3 + adst + ae3; al3 = (al3 > 0.f) ? al3 : 0.2f * al3;
        float ex0 = __expf(al0), ex1 = __expf(al1);
        float ex2 = __expf(al2), ex3 = __expf(al3);
        den += (ex0 + ex1) + (ex2 + ex3);
        acc.x += ex0 * b2f(x0.x) + ex1 * b2f(x1.x) + ex2 * b2f(x2.x) + ex3 * b2f(x3.x);
        acc.y += ex0 * b2f(x0.y) + ex1 * b2f(x1.y) + ex2 * b2f(x2.y) + ex3 * b2f(x3.y);
        acc.z += ex0 * b2f(x0.z) + ex1 * b2f(x1.z) + ex2 * b2f(x2.z) + ex3 * b2f(x3.z);
        acc.w += ex0 * b2f(x0.w) + ex1 * b2f(x1.w) + ex2 * b2f(x2.w) + ex3 * b2f(x3.w);
    }
    for (; p + 2 <= e; p += 2) {
        int s0 = col_src[p],     s1 = col_src[p + 1];
        int e0 = col_eid[p],     e1 = col_eid[p + 1];
        float as0 = a_src[s0 * 8 + nh];
        float as1 = a_src[s1 * 8 + nh];
        float ae0 = b2f(a_e_all[(size_t)e0 * 32 + aeo]);
        float ae1 = b2f(a_e_all[(size_t)e1 * 32 + aeo]);
        ushort4 x0 = *(const ushort4*)(xs + (size_t)s0 * HDIM + c);
        ushort4 x1 = *(const ushort4*)(xs + (size_t)s1 * HDIM + c);
        float al0 = as0 + adst + ae0; al0 = (al0 > 0.f) ? al0 : 0.2f * al0;
        float al1 = as1 + adst + ae1; al1 = (al1 > 0.f) ? al1 : 0.2f * al1;
        float ex0 = __expf(al0);
        float ex1 = __expf(al1);
        den += ex0 + ex1;
        acc.x += ex0 * b2f(x0.x) + ex1 * b2f(x1.x);
        acc.y += ex0 * b2f(x0.y) + ex1 * b2f(x1.y);
        acc.z += ex0 * b2f(x0.z) + ex1 * b2f(x1.z);
        acc.w += ex0 * b2f(x0.w) + ex1 * b2f(x1.w);
    }
    if (p < e) {
        int s0 = col_src[p];
        int e0 = col_eid[p];
        float al = a_src[s0 * 8 + nh] + adst + b2f(a_e_all[(size_t)e0 * 32 + aeo]);
        al = (al > 0.f) ? al : 0.2f * al;
        float ex = __expf(al);
        den += ex;
        ushort4 x4 = *(const ushort4*)(xs + (size_t)s0 * HDIM + c);
        acc.x += ex * b2f(x4.x); acc.y += ex * b2f(x4.y);
        acc.z += ex * b2f(x4.z); acc.w += ex * b2f(x4.w);
    }
    float inv = 1.f / (den + 1e-16f);
    float4 b4 = *(const float4*)(bias_l + c);
    ushort4 o4;
    o4.x = f2bf(acc.x * inv + b4.x);
    o4.y = f2bf(acc.y * inv + b4.y);
    o4.z = f2bf(acc.z * inv + b4.z);
    o4.w = f2bf(acc.w * inv + b4.w);
    *(ushort4*)(outb + (size_t)n * HDIM + c) = o4;
}

// ---------------------------------------------------------------------------
// BatchNorm stats, stage 1
// ---------------------------------------------------------------------------
__global__ __launch_bounds__(256)
void bn_stats1_kernel(const u16* __restrict__ outb, float* __restrict__ gsum,
                      float* __restrict__ gsq) {
    __shared__ float lsum[8][HDIM];
    __shared__ float lsq[8][HDIM];
    const int t = threadIdx.x;
    const int b = blockIdx.x;            // 800 blocks
    const int c0 = (t & 31) * 8;
    const int g = t >> 5;
    const size_t base = (size_t)b * 64 * HDIM;
    float s[8] = {}, q[8] = {};
#pragma unroll
    for (int i = 0; i < 8; ++i) {
        const u16* p = outb + base + i * 2048 + t * 8;
        ushort4 u0 = *(const ushort4*)p;
        ushort4 u1 = *(const ushort4*)(p + 4);
        float v0 = b2f(u0.x), v1 = b2f(u0.y), v2 = b2f(u0.z), v3 = b2f(u0.w);
        float v4 = b2f(u1.x), v5 = b2f(u1.y), v6 = b2f(u1.z), v7 = b2f(u1.w);
        s[0] += v0; q[0] += v0 * v0;  s[1] += v1; q[1] += v1 * v1;
        s[2] += v2; q[2] += v2 * v2;  s[3] += v3; q[3] += v3 * v3;
        s[4] += v4; q[4] += v4 * v4;  s[5] += v5; q[5] += v5 * v5;
        s[6] += v6; q[6] += v6 * v6;  s[7] += v7; q[7] += v7 * v7;
    }
#pragma unroll
    for (int j = 0; j < 8; ++j) { lsum[g][c0 + j] = s[j]; lsq[g][c0 + j] = q[j]; }
    __syncthreads();
    float ts = 0.f, tq = 0.f;
#pragma unroll
    for (int gg = 0; gg < 8; ++gg) { ts += lsum[gg][t]; tq += lsq[gg][t]; }
    int slot = b & (BN_SLOTS - 1);
    atomicAdd(&gsum[slot * HDIM + t], ts);
    atomicAdd(&gsq[slot * HDIM + t], tq);
}

// stage 2: fold 16 slots -> mu, inv; zero slots for next layer (graph-safe)
__global__ __launch_bounds__(256)
void bn_stats2_kernel(float* __restrict__ gsum, float* __restrict__ gsq,
                      float* __restrict__ mu, float* __restrict__ inv) {
    int c = threadIdx.x;
    float s = 0.f, s2 = 0.f;
#pragma unroll
    for (int b = 0; b < BN_SLOTS; ++b) {
        s += gsum[b * HDIM + c];
        s2 += gsq[b * HDIM + c];
        gsum[b * HDIM + c] = 0.f;
        gsq[b * HDIM + c] = 0.f;
    }
    float m = s / (float)N_NODES;
    float var = s2 / (float)N_NODES - m * m;
    mu[c] = m;
    inv[c] = rsqrtf(var + 1e-5f);
}

__global__ __launch_bounds__(256)
void bn_apply_kernel(const u16* __restrict__ outb, const float* __restrict__ mu,
                     const float* __restrict__ inv, const float* __restrict__ gamma_l,
                     const float* __restrict__ beta_l, u16* __restrict__ h, int addres) {
    int idx = blockIdx.x * 256 + threadIdx.x;       // N*H/4 threads
    int c = (idx & 63) << 2;
    ushort4 v4 = *(const ushort4*)(outb + (size_t)idx * 4);
    float4 m4 = *(const float4*)(mu + c);
    float4 i4 = *(const float4*)(inv + c);
    float4 g4 = *(const float4*)(gamma_l + c);
    float4 b4 = *(const float4*)(beta_l + c);
    float v0 = fmaxf(g4.x * (b2f(v4.x) - m4.x) * i4.x + b4.x, 0.f);
    float v1 = fmaxf(g4.y * (b2f(v4.y) - m4.y) * i4.y + b4.y, 0.f);
    float v2 = fmaxf(g4.z * (b2f(v4.z) - m4.z) * i4.z + b4.z, 0.f);
    float v3 = fmaxf(g4.w * (b2f(v4.w) - m4.w) * i4.w + b4.w, 0.f);
    if (addres) {
        ushort4 h4 = *(const ushort4*)(h + (size_t)idx * 4);
        v0 += b2f(h4.x); v1 += b2f(h4.y); v2 += b2f(h4.z); v3 += b2f(h4.w);
    }
    ushort4 o4;
    o4.x = f2bf(v0); o4.y = f2bf(v1); o4.z = f2bf(v2); o4.w = f2bf(v3);
    *(ushort4*)(h + (size_t)idx * 4) = o4;
}

// ---------------------------------------------------------------------------
// MFMA MHA: one 64-thread block per (graph, head), packed qkv (stride 768).
// v2: all Q/K fragments prefetched up front (2x MLP); V staged via uint4.
// ---------------------------------------------------------------------------
__global__ __launch_bounds__(64)
void mha_attn_kernel(const u16* __restrict__ qkv, u16* __restrict__ o) {
    const int g = blockIdx.x >> 3;
    const int head = blockIdx.x & 7;
    const int l = threadIdx.x;
    __shared__ u16 VT[DHEAD][132];     // V^T: [d][key], keys zero-padded to 128
    __shared__ u16 P[16][132];         // row-tile of probabilities (bf16)
    const size_t base = (size_t)g * NPGRAPH * 768 + head * 32;

    // prefetch all K and Q fragments (14 independent 16B loads per lane)
    bf16x8 kf[7], qf[7];
#pragma unroll
    for (int n = 0; n < 7; ++n) {
        int r = n * 16 + (l & 15);
        kf[n] = *(const bf16x8*)(qkv + base + (size_t)r * 768 + 256 + ((l >> 4) << 3));
        qf[n] = *(const bf16x8*)(qkv + base + (size_t)r * 768 + ((l >> 4) << 3));
    }
    // stage V^T via uint4: 8 iters x (16 rows x 4 chunks), zero-pad keys>=100
    for (int m0 = 0; m0 < 128; m0 += 16) {
        int m = m0 + (l >> 2);
        int d0 = (l & 3) * 8;
        uint4 v = make_uint4(0u, 0u, 0u, 0u);
        if (m < 100) v = *(const uint4*)(qkv + base + (size_t)m * 768 + 512 + d0);
        u16 tmp[8];
        *(uint4*)tmp = v;
#pragma unroll
        for (int j = 0; j < 8; ++j) VT[d0 + j][m] = tmp[j];
    }
    __syncthreads();
    bf16x8 vf[2][4];
#pragma unroll
    for (int dt = 0; dt < 2; ++dt)
#pragma unroll
        for (int kc = 0; kc < 4; ++kc)
            vf[dt][kc] = *(const bf16x8*)(&VT[dt * 16 + (l & 15)][kc * 32 + ((l >> 4) << 3)]);

    const float SC = 0.17677669529663687f;   // 1/sqrt(32)
    const bool c6ok = (96 + (l & 15)) < 100;

    for (int mt = 0; mt < 7; ++mt) {
        f32x4 sa[7];
#pragma unroll
        for (int n = 0; n < 7; ++n) {
            f32x4 z = {0.f, 0.f, 0.f, 0.f};
            sa[n] = __builtin_amdgcn_mfma_f32_16x16x32_bf16(qf[mt], kf[n], z, 0, 0, 0);
        }
        float linv[4];
#pragma unroll
        for (int j = 0; j < 4; ++j) {
            float m = -1e30f;
#pragma unroll
            for (int n = 0; n < 6; ++n) m = fmaxf(m, sa[n][j]);
            if (c6ok) m = fmaxf(m, sa[6][j]);
            m *= SC;
#pragma unroll
            for (int off = 1; off < 16; off <<= 1) m = fmaxf(m, __shfl_xor(m, off));
            float ls = 0.f;
            float pv[7];
#pragma unroll
            for (int n = 0; n < 7; ++n) {
                float p_ = 0.f;
                if (n < 6 || c6ok) p_ = __expf(SC * sa[n][j] - m);
                pv[n] = p_;
                ls += p_;
            }
#pragma unroll
            for (int off = 1; off < 16; off <<= 1) ls += __shfl_xor(ls, off);
            linv[j] = 1.f / ls;
            int rt = ((l >> 4) << 2) + j;
#pragma unroll
            for (int n = 0; n < 7; ++n) P[rt][n * 16 + (l & 15)] = f2bf(pv[n]);
            P[rt][112 + (l & 15)] = 0;
        }
        __syncthreads();
        f32x4 oa[2] = {};
#pragma unroll
        for (int kc = 0; kc < 4; ++kc) {
            bf16x8 pf = *(const bf16x8*)(&P[l & 15][kc * 32 + ((l >> 4) << 3)]);
            oa[0] = __builtin_amdgcn_mfma_f32_16x16x32_bf16(pf, vf[0][kc], oa[0], 0, 0, 0);
            oa[1] = __builtin_amdgcn_mfma_f32_16x16x32_bf16(pf, vf[1][kc], oa[1], 0, 0, 0);
        }
        int r0 = mt * 16 + ((l >> 4) << 2);
#pragma unroll
        for (int dt = 0; dt < 2; ++dt)
#pragma unroll
            for (int j = 0; j < 4; ++j) {
                int r = r0 + j;
                if (r < 100)
                    o[(size_t)(g * NPGRAPH + r) * HDIM + head * 32 + dt * 16 + (l & 15)] =
                        f2bf(oa[dt][j] * linv[j]);
            }
        __syncthreads();
    }
}

// mean pool over nodes per graph
__global__ __launch_bounds__(256)
void pool_kernel(const u16* __restrict__ o2, u16* __restrict__ pooled) {
    int g = blockIdx.x;
    int c = threadIdx.x;
    float s = 0.f;
    for (int r = 0; r < NPGRAPH; ++r) s += b2f(o2[((size_t)g * NPGRAPH + r) * HDIM + c]);
    pooled[g * HDIM + c] = f2bf(s * 0.01f);
}

// task heads
__global__ __launch_bounds__(64)
void heads_kernel(const u16* __restrict__ s2, const float* __restrict__ w1,
                  const float* __restrict__ b1, const float* __restrict__ w2,
                  const float* __restrict__ b2, float* __restrict__ out) {
    int g = blockIdx.x / TASKS;
    int tt = blockIdx.x % TASKS;
    int d = threadIdx.x;   // 64
    float s = b1[tt * 64 + d];
    const u16* srow = s2 + (size_t)g * 128;
    const float* wcol = w1 + (size_t)tt * 128 * 64 + d;
    for (int k = 0; k < 128; ++k) s += b2f(srow[k]) * wcol[k * 64];
    s = fmaxf(s, 0.f);
    float v = s * w2[tt * 64 + d];
#pragma unroll
    for (int off = 32; off >= 1; off >>= 1) v += __shfl_down(v, off);
    if (d == 0) out[g * TASKS + tt] = v + b2[tt];
}

// ---------------------------------------------------------------------------
extern "C" void kernel_launch(void* const* d_in, const int* in_sizes, int n_in,
                              void* d_out, int out_size, void* d_ws, size_t ws_size,
                              hipStream_t stream) {
    const float* x          = (const float*)d_in[0];
    const float* edge_attr  = (const float*)d_in[1];
    const int*   edge_index = (const int*)d_in[2];
    const float* atom_w     = (const float*)d_in[4];
    const float* atom_b     = (const float*)d_in[5];
    const float* edge_w     = (const float*)d_in[6];
    const float* edge_b     = (const float*)d_in[7];
    const float* gat_lin_w  = (const float*)d_in[8];
    const float* gat_lin_ew = (const float*)d_in[9];
    const float* att_src    = (const float*)d_in[10];
    const float* att_dst    = (const float*)d_in[11];
    const float* att_edge   = (const float*)d_in[12];
    const float* gat_bias   = (const float*)d_in[13];
    const float* bn_gamma   = (const float*)d_in[14];
    const float* bn_beta    = (const float*)d_in[15];
    const float* mha_in_w   = (const float*)d_in[16];
    const float* mha_in_b   = (const float*)d_in[17];
    const float* mha_out_w  = (const float*)d_in[18];
    const float* mha_out_b  = (const float*)d_in[19];
    const float* sh_w1      = (const float*)d_in[20];
    const float* sh_b1      = (const float*)d_in[21];
    const float* sh_w2      = (const float*)d_in[22];
    const float* sh_b2      = (const float*)d_in[23];
    const float* head_w1    = (const float*)d_in[24];
    const float* head_b1    = (const float*)d_in[25];
    const float* head_w2    = (const float*)d_in[26];
    const float* head_b2    = (const float*)d_in[27];
    float* out = (float*)d_out;

    const int* src = edge_index;
    const int* dst = edge_index + N_EDGES;

    // ---- workspace layout (bytes, 256B aligned; ~112 MB) ----
    size_t off = 0;
    auto alloc = [&](size_t bytes) -> void* {
        void* p = (char*)d_ws + off;
        off += (bytes + 255) & ~(size_t)255;
        return p;
    };
    const size_t NHB = (size_t)N_NODES * HDIM * sizeof(u16);      // 26,214,400
    u16* h_buf = (u16*)alloc(NHB);
    char* region1 = (char*)alloc((size_t)N_NODES * 768 * sizeof(u16));   // 78.6MB
    u16* xs_buf  = (u16*)region1;
    u16* out_buf = (u16*)(region1 + NHB);
    u16* a_e_all = (u16*)(region1 + 2 * NHB);
    u16* qkv_buf = (u16*)region1;     // phase2: xs/outb/a_e dead
    u16* o2_buf  = (u16*)region1;     // phase3: qkv dead after attention
    u16* o_buf   = h_buf;             // h dead after qkv GEMM
    u16* x_bf    = out_buf;           // alias: dead before aggregate
    float* a_src_b = (float*)alloc((size_t)N_NODES * 8 * sizeof(float));
    float* a_dst_b = (float*)alloc((size_t)N_NODES * 8 * sizeof(float));
    float* gsum    = (float*)alloc(BN_SLOTS * HDIM * sizeof(float));
    float* gsq     = (float*)alloc(BN_SLOTS * HDIM * sizeof(float));
    float* mu_b    = (float*)alloc(HDIM * sizeof(float));
    float* inv_b   = (float*)alloc(HDIM * sizeof(float));
    float* P_e     = (float*)alloc(LAYERS * HDIM * 8 * sizeof(float));
    float* Qm      = (float*)alloc(256 * sizeof(float));
    float* c0m     = (float*)alloc(32 * sizeof(float));
    u16* atom_wt   = (u16*)alloc((size_t)HDIM * FATOM * sizeof(u16));
    u16* lin_wt    = (u16*)alloc((size_t)LAYERS * HDIM * HDIM * sizeof(u16));
    u16* in_w_bf   = (u16*)alloc((size_t)768 * HDIM * sizeof(u16));
    u16* out_w_bf  = (u16*)alloc((size_t)HDIM * HDIM * sizeof(u16));
    u16* sh1_t     = (u16*)alloc((size_t)HDIM * HDIM * sizeof(u16));
    u16* sh2_t     = (u16*)alloc((size_t)128 * HDIM * sizeof(u16));
    u16* pooled    = (u16*)alloc((size_t)GRAPHS * HDIM * sizeof(u16));
    u16* s1_b      = (u16*)alloc((size_t)GRAPHS * HDIM * sizeof(u16));
    u16* s2_b      = (u16*)alloc((size_t)GRAPHS * 128 * sizeof(u16));
    int* deg       = (int*)alloc(N_NODES * sizeof(int));
    int* row_ptr   = (int*)alloc((N_NODES + 256) * sizeof(int));
    int* cursor    = (int*)alloc(N_NODES * sizeof(int));
    int* col_src   = (int*)alloc(NFULL * sizeof(int));
    int* col_eid   = (int*)alloc(NFULL * sizeof(int));
    int* bsum      = (int*)alloc(64 * sizeof(int));
    (void)ws_size; (void)in_sizes; (void)n_in; (void)out_size;

    // ---- weight + input bf16 conversion ----
    convert_t_kernel<<<(HDIM * FATOM + 255) / 256, 256, 0, stream>>>(atom_w, atom_wt, FATOM, HDIM);
    convert_t4_kernel<<<(LAYERS * HDIM * HDIM) / 256, 256, 0, stream>>>(gat_lin_w, lin_wt);
    convert_kernel<<<(768 * HDIM + 255) / 256, 256, 0, stream>>>(mha_in_w, in_w_bf, 768 * HDIM);
    convert_kernel<<<(HDIM * HDIM + 255) / 256, 256, 0, stream>>>(mha_out_w, out_w_bf, HDIM * HDIM);
    convert_t_kernel<<<(HDIM * HDIM + 255) / 256, 256, 0, stream>>>(sh_w1, sh1_t, HDIM, HDIM);
    convert_t_kernel<<<(HDIM * 128 + 255) / 256, 256, 0, stream>>>(sh_w2, sh2_t, HDIM, 128);
    convert_kernel<<<(N_NODES * FATOM + 255) / 256, 256, 0, stream>>>(x, x_bf, N_NODES * FATOM);

    // ---- CSR (3-stage scan) ----
    hipMemsetAsync(deg, 0, N_NODES * sizeof(int), stream);
    edge_hist_kernel<<<(N_EDGES + 255) / 256, 256, 0, stream>>>(dst, deg);
    scan1_kernel<<<SCAN_BLOCKS, 1024, 0, stream>>>(deg, row_ptr, bsum);
    scan2_kernel<<<1, 64, 0, stream>>>(bsum, row_ptr);
    scan3_kernel<<<N_NODES / 256, 256, 0, stream>>>(row_ptr, bsum);
    selfloop_init_kernel<<<(N_NODES + 255) / 256, 256, 0, stream>>>(row_ptr, cursor, col_src, col_eid);
    scatter_kernel<<<(N_EDGES + 255) / 256, 256, 0, stream>>>(src, dst, cursor, col_src, col_eid);

    // ---- attention-logit edge projections ----
    proj_pe_kernel<<<32, 256, 0, stream>>>(gat_lin_ew, att_edge, P_e);
    proj_q_kernel<<<1, 256, 0, stream>>>(edge_w, edge_b, P_e, Qm, c0m);
    ae_real_kernel<<<N_EDGES / 8, 256, 0, stream>>>(edge_attr, Qm, c0m, a_e_all);
    ae_self_kernel<<<N_NODES / 8, 256, 0, stream>>>(
        edge_attr, row_ptr, col_eid, Qm, c0m, a_e_all);

    // ---- atom encoder ----
    gemm_mfma_kernel<true, false><<<(HDIM / 128) * (N_NODES / 128), 256, 0, stream>>>(
        x_bf, atom_wt, atom_b, h_buf, N_NODES, FATOM, HDIM);

    // ---- GAT layers ----
    hipMemsetAsync(gsum, 0, BN_SLOTS * HDIM * sizeof(float), stream);
    hipMemsetAsync(gsq, 0, BN_SLOTS * HDIM * sizeof(float), stream);
    for (int li = 0; li < LAYERS; ++li) {
        gemm_mfma_kernel<false, false><<<(HDIM / 128) * (N_NODES / 128), 256, 0, stream>>>(
            h_buf, lin_wt + (size_t)li * HDIM * HDIM, nullptr, xs_buf, N_NODES, HDIM, HDIM);
        gat_asd_kernel<<<N_NODES / 4, 256, 0, stream>>>(
            xs_buf, att_src + li * HDIM, att_dst + li * HDIM, a_src_b, a_dst_b);
        gat_aggregate_kernel<<<N_NODES / 4, 256, 0, stream>>>(
            xs_buf, a_src_b, a_dst_b, a_e_all, row_ptr, col_src, col_eid,
            gat_bias + li * HDIM, out_buf, li);
        bn_stats1_kernel<<<N_NODES / 64, 256, 0, stream>>>(out_buf, gsum, gsq);
        bn_stats2_kernel<<<1, 256, 0, stream>>>(gsum, gsq, mu_b, inv_b);
        bn_apply_kernel<<<(N_NODES * HDIM / 4) / 256, 256, 0, stream>>>(
            out_buf, mu_b, inv_b, bn_gamma + li * HDIM, bn_beta + li * HDIM, h_buf, li > 0 ? 1 : 0);
    }

    // ---- MHA (combined qkv GEMM, r11 structure) ----
    gemm_mfma_kernel<true, false><<<(768 / 128) * (N_NODES / 128), 256, 0, stream>>>(
        h_buf, in_w_bf, mha_in_b, qkv_buf, N_NODES, HDIM, 768);
    mha_attn_kernel<<<GRAPHS * NHEADS, 64, 0, stream>>>(qkv_buf, o_buf);
    gemm_mfma_kernel<true, false><<<(HDIM / 128) * (N_NODES / 128), 256, 0, stream>>>(
        o_buf, out_w_bf, mha_out_b, o2_buf, N_NODES, HDIM, HDIM);
    pool_kernel<<<GRAPHS, 256, 0, stream>>>(o2_buf, pooled);

    // ---- shared MLP + task heads ----
    gemm_mfma_kernel<true, true><<<(HDIM / 128) * (GRAPHS / 128), 256, 0, stream>>>(
        pooled, sh1_t, sh_b1, s1_b, GRAPHS, HDIM, HDIM);
    gemm_mfma_kernel<true, true><<<(128 / 128) * (GRAPHS / 128), 256, 0, stream>>>(
        s1_b, sh2_t, sh_b2, s2_b, GRAPHS, HDIM, 128);
    heads_kernel<<<GRAPHS * TASKS, 64, 0, stream>>>(
        s2_b, head_w1, head_b1, head_w2, head_b2, out);
}

// Round 15
// 871.012 us; speedup vs baseline: 1.0543x; 1.0543x over previous
//
#include <hip/hip_runtime.h>
#include <hip/hip_bf16.h>

#define N_NODES 51200
#define N_EDGES 300000
#define NFULL   351200   // E + N
#define GRAPHS  512
#define NPGRAPH 100
#define FATOM   64
#define FEDGE   8
#define HDIM    256
#define NHEADS  8
#define DHEAD   32
#define LAYERS  4
#define TASKS   5
#define BN_SLOTS 16
#define SCAN_BLOCKS 50   // 50 * 1024 = 51200

typedef unsigned short u16;
typedef __attribute__((ext_vector_type(8))) short bf16x8;
typedef __attribute__((ext_vector_type(4))) float f32x4;

__device__ __forceinline__ float b2f(u16 u) {
    return __uint_as_float(((unsigned)u) << 16);
}
__device__ __forceinline__ u16 f2bf(float f) {
    unsigned u = __float_as_uint(f);
    unsigned r = u + 0x7fffu + ((u >> 16) & 1u);   // round-to-nearest-even
    return (u16)(r >> 16);
}

// ---------------------------------------------------------------------------
// fp32 -> bf16 flat convert
// ---------------------------------------------------------------------------
__global__ __launch_bounds__(256)
void convert_kernel(const float* __restrict__ in, u16* __restrict__ out, int n) {
    int i = blockIdx.x * 256 + threadIdx.x;
    if (i < n) out[i] = f2bf(in[i]);
}

// fp32 [R][C] -> bf16 [C][R]
__global__ __launch_bounds__(256)
void convert_t_kernel(const float* __restrict__ in, u16* __restrict__ out, int R, int C) {
    int idx = blockIdx.x * 256 + threadIdx.x;
    if (idx >= R * C) return;
    int c = idx / R, r = idx % R;
    out[idx] = f2bf(in[(size_t)r * C + c]);
}

// 4 layers of [256][256] transposed in one launch
__global__ __launch_bounds__(256)
void convert_t4_kernel(const float* __restrict__ in, u16* __restrict__ out) {
    int idx = blockIdx.x * 256 + threadIdx.x;   // 4*65536
    int li = idx >> 16, rem = idx & 65535;
    int c = rem >> 8, r = rem & 255;
    out[idx] = f2bf(in[(size_t)li * 65536 + r * 256 + c]);
}

// ---------------------------------------------------------------------------
// MFMA bf16 GEMM (round-11 verified): BM=BN=128, BK=64, 4 waves 2x2,
// XCD chunk swizzle, LDS epilogue -> coalesced 16B stores.
// ---------------------------------------------------------------------------
template<bool BIAS, bool RELU>
__global__ __launch_bounds__(256, 2)
void gemm_mfma_kernel(const u16* __restrict__ A, const u16* __restrict__ Bt,
                      const float* __restrict__ bias, u16* __restrict__ C,
                      int M, int K, int N) {
    __shared__ u16 smem[136 * 128];
    u16* As = smem;                          // [128][64]
    u16* Bs = smem + 128 * 64;               // [128][64]
    const int t = threadIdx.x;
    const int lane = t & 63;
    const int w = t >> 6;
    const int wr = w >> 1, wc = w & 1;

    const int nwg = (int)gridDim.x;
    const int bid = (int)blockIdx.x;
    const int q = nwg >> 3, r = nwg & 7;
    const int xcd = bid & 7, idx0 = bid >> 3;
    const int wgid = (xcd < r) ? xcd * (q + 1) + idx0
                               : r * (q + 1) + (xcd - r) * q + idx0;
    const int nx = N >> 7;
    const int bn = (wgid % nx) * 128;
    const int bm = (wgid / nx) * 128;

    f32x4 acc[4][4] = {};

    for (int kt = 0; kt < K; kt += 64) {
        uint4 ra[4], rb[4];
#pragma unroll
        for (int i = 0; i < 4; ++i) {
            int idx = i * 256 + t;
            int row = idx >> 3, ch = idx & 7;
            ra[i] = *(const uint4*)(A + (size_t)(bm + row) * K + kt + ch * 8);
            rb[i] = *(const uint4*)(Bt + (size_t)(bn + row) * K + kt + ch * 8);
        }
        __syncthreads();
#pragma unroll
        for (int i = 0; i < 4; ++i) {
            int idx = i * 256 + t;
            int row = idx >> 3, ch = idx & 7;
            int sw = ch ^ (row & 7);
            *(uint4*)((char*)As + row * 128 + sw * 16) = ra[i];
            *(uint4*)((char*)Bs + row * 128 + sw * 16) = rb[i];
        }
        __syncthreads();
#pragma unroll
        for (int kk = 0; kk < 2; ++kk) {
            bf16x8 af[4], bf[4];
#pragma unroll
            for (int m = 0; m < 4; ++m) {
                int rr = wr * 64 + m * 16 + (lane & 15);
                int ch = kk * 4 + (lane >> 4);
                af[m] = *(const bf16x8*)((const char*)As + rr * 128 + ((ch ^ (rr & 7)) << 4));
            }
#pragma unroll
            for (int n = 0; n < 4; ++n) {
                int rr = wc * 64 + n * 16 + (lane & 15);
                int ch = kk * 4 + (lane >> 4);
                bf[n] = *(const bf16x8*)((const char*)Bs + rr * 128 + ((ch ^ (rr & 7)) << 4));
            }
#pragma unroll
            for (int m = 0; m < 4; ++m)
#pragma unroll
                for (int n = 0; n < 4; ++n)
                    acc[m][n] = __builtin_amdgcn_mfma_f32_16x16x32_bf16(
                        af[m], bf[n], acc[m][n], 0, 0, 0);
        }
    }
    __syncthreads();
#pragma unroll
    for (int m = 0; m < 4; ++m)
#pragma unroll
        for (int n = 0; n < 4; ++n) {
            int coll = wc * 64 + n * 16 + (lane & 15);
            float bv = BIAS ? bias[bn + coll] : 0.f;
#pragma unroll
            for (int j = 0; j < 4; ++j) {
                float v = acc[m][n][j] + bv;
                if (RELU) v = fmaxf(v, 0.f);
                int rowl = wr * 64 + m * 16 + (lane >> 4) * 4 + j;
                smem[rowl * 136 + coll] = f2bf(v);
            }
        }
    __syncthreads();
#pragma unroll
    for (int p = 0; p < 8; ++p) {
        int rowl = p * 16 + (t >> 4);
        uint4 v = *(const uint4*)(smem + rowl * 136 + (t & 15) * 8);
        *(uint4*)(C + (size_t)(bm + rowl) * N + bn + (t & 15) * 8) = v;
    }
}

// ---------------------------------------------------------------------------
// Degree histogram (int atomics)
// ---------------------------------------------------------------------------
__global__ __launch_bounds__(256)
void edge_hist_kernel(const int* __restrict__ dst, int* __restrict__ deg) {
    int e = blockIdx.x * 256 + threadIdx.x;
    if (e >= N_EDGES) return;
    atomicAdd(&deg[dst[e]], 1);
}

// ---------------------------------------------------------------------------
// Three-stage exclusive scan of (deg[i]+1) -> row_ptr[0..N]
// ---------------------------------------------------------------------------
__global__ __launch_bounds__(1024)
void scan1_kernel(const int* __restrict__ deg, int* __restrict__ row_ptr,
                  int* __restrict__ bsum) {
    __shared__ int buf[1024];
    const int b = blockIdx.x, t = threadIdx.x;
    const int i = b * 1024 + t;
    int v = deg[i] + 1;
    buf[t] = v;
    __syncthreads();
    for (int off = 1; off < 1024; off <<= 1) {
        int x = (t >= off) ? buf[t - off] : 0;
        __syncthreads();
        buf[t] += x;
        __syncthreads();
    }
    row_ptr[i] = buf[t] - v;               // exclusive within block
    if (t == 1023) bsum[b] = buf[t];
}

__global__ __launch_bounds__(64)
void scan2_kernel(int* __restrict__ bsum, int* __restrict__ row_ptr) {
    int t = threadIdx.x;                   // one wave
    int orig = (t < SCAN_BLOCKS) ? bsum[t] : 0;
    int v = orig;
    for (int off = 1; off < 64; off <<= 1) {
        int x = __shfl_up(v, off);
        if (t >= off) v += x;
    }
    if (t < SCAN_BLOCKS) bsum[t] = v - orig;   // exclusive block offset
    if (t == SCAN_BLOCKS - 1) row_ptr[N_NODES] = v;
}

__global__ __launch_bounds__(256)
void scan3_kernel(int* __restrict__ row_ptr, const int* __restrict__ bsum) {
    int i = blockIdx.x * 256 + threadIdx.x;
    if (i >= N_NODES) return;
    row_ptr[i] += bsum[i >> 10];
}

__global__ __launch_bounds__(256)
void selfloop_init_kernel(const int* __restrict__ row_ptr, int* __restrict__ cursor,
                          int* __restrict__ col_src, int* __restrict__ col_eid) {
    int n = blockIdx.x * 256 + threadIdx.x;
    if (n >= N_NODES) return;
    cursor[n] = row_ptr[n];
    int pos = row_ptr[n + 1] - 1;
    col_src[pos] = n;
    col_eid[pos] = N_EDGES + n;
}

__global__ __launch_bounds__(256)
void scatter_kernel(const int* __restrict__ src, const int* __restrict__ dst,
                    int* __restrict__ cursor, int* __restrict__ col_src,
                    int* __restrict__ col_eid) {
    int e = blockIdx.x * 256 + threadIdx.x;
    if (e >= N_EDGES) return;
    int d = dst[e];
    int pos = atomicAdd(&cursor[d], 1);
    col_src[pos] = src[e];
    col_eid[pos] = e;
}

// ---------------------------------------------------------------------------
// P_e[li][k][nh] = sum_d lin_edge_w[li][k][nh*32+d] * att_edge[li][nh][d]
// ---------------------------------------------------------------------------
__global__ __launch_bounds__(256)
void proj_pe_kernel(const float* __restrict__ lin_edge_w, const float* __restrict__ att_edge,
                    float* __restrict__ P_e) {
    int idx = blockIdx.x * 256 + threadIdx.x;   // 4*256*8 = 8192
    int li = idx >> 11;
    int rem = idx & 2047;
    int k = rem >> 3, nh = rem & 7;
    const float* w = lin_edge_w + (size_t)li * HDIM * HDIM + (size_t)k * HDIM + nh * DHEAD;
    const float* a = att_edge + li * HDIM + nh * DHEAD;
    float s = 0.f;
#pragma unroll
    for (int d = 0; d < DHEAD; ++d) s += w[d] * a[d];
    P_e[idx] = s;
}

// Qm[li][f][nh] = sum_k edge_w[f][k] * P_e[li][k][nh];  c0[li][nh] = edge_b @ P_e
__global__ __launch_bounds__(256)
void proj_q_kernel(const float* __restrict__ edge_w, const float* __restrict__ edge_b,
                   const float* __restrict__ P_e, float* __restrict__ Qm,
                   float* __restrict__ c0m) {
    int t = threadIdx.x;          // 256 = 4*8*8
    int li = t >> 6, f = (t >> 3) & 7, nh = t & 7;
    const float* pe = P_e + li * 2048;
    float q = 0.f;
    for (int k = 0; k < HDIM; ++k) q += edge_w[f * HDIM + k] * pe[k * 8 + nh];
    Qm[t] = q;
    if (t < 32) {
        int li2 = t >> 3, nh2 = t & 7;
        const float* pe2 = P_e + li2 * 2048;
        float c = 0.f;
        for (int k = 0; k < HDIM; ++k) c += edge_b[k] * pe2[k * 8 + nh2];
        c0m[t] = c;
    }
}

// a_e for real edges: [E,32] bf16 ; 8 edges x 32 outputs per block
__global__ __launch_bounds__(256)
void ae_real_kernel(const float* __restrict__ edge_attr, const float* __restrict__ Qm,
                    const float* __restrict__ c0m, u16* __restrict__ a_e_all) {
    __shared__ float ea_s[8][8];
    __shared__ float Qs[256];
    __shared__ float c0s[32];
    const int t = threadIdx.x;
    const int e0 = blockIdx.x * 8;
    if (t < 64) ea_s[t >> 3][t & 7] = edge_attr[(size_t)e0 * 8 + t];
    Qs[t] = Qm[t];
    if (t < 32) c0s[t] = c0m[t];
    __syncthreads();
    int el = t >> 5, o = t & 31;
    int li = o >> 3, nh = o & 7;
    float v = c0s[o];
#pragma unroll
    for (int f = 0; f < 8; ++f) v += ea_s[el][f] * Qs[li * 64 + f * 8 + nh];
    a_e_all[(size_t)(e0 + el) * 32 + o] = f2bf(v);
}

// a_e for self loops (rows E..E+N-1): per-node edge-attr sums via CSR walk
__global__ __launch_bounds__(256)
void ae_self_kernel(const float* __restrict__ edge_attr, const int* __restrict__ row_ptr,
                    const int* __restrict__ col_eid, const float* __restrict__ Qm,
                    const float* __restrict__ c0m, u16* __restrict__ a_e_all) {
    __shared__ float ea_s[8][8];
    __shared__ int deg_s[8];
    __shared__ float Qs[256];
    __shared__ float c0s[32];
    const int t = threadIdx.x;
    const int n0 = blockIdx.x * 8;
    Qs[t] = Qm[t];
    if (t < 32) c0s[t] = c0m[t];
    if (t < 64) {
        int el = t >> 3, f = t & 7;
        int n = n0 + el;
        int s = row_ptr[n], e = row_ptr[n + 1] - 1;   // exclude self-loop slot
        float acc = 0.f;
        for (int p = s; p < e; ++p)
            acc += edge_attr[(size_t)col_eid[p] * FEDGE + f];
        ea_s[el][f] = acc;
        if (f == 0) deg_s[el] = e - s;
    }
    __syncthreads();
    int el = t >> 5, o = t & 31;
    int li = o >> 3, nh = o & 7;
    int dg = deg_s[el];
    float v = 0.f;
    if (dg > 0) {
        float invd = 1.f / (float)dg;
        v = c0s[o];
#pragma unroll
        for (int f = 0; f < 8; ++f) v += ea_s[el][f] * invd * Qs[li * 64 + f * 8 + nh];
    }
    a_e_all[(size_t)(N_EDGES + n0 + el) * 32 + o] = f2bf(v);
}

// ---------------------------------------------------------------------------
// a_src / a_dst from xs(bf16 ws): one wave per node
// ---------------------------------------------------------------------------
__global__ __launch_bounds__(256)
void gat_asd_kernel(const u16* __restrict__ xs, const float* __restrict__ att_src_l,
                    const float* __restrict__ att_dst_l, float* __restrict__ a_src,
                    float* __restrict__ a_dst) {
    int node = (blockIdx.x << 2) + (threadIdx.x >> 6);
    int lane = threadIdx.x & 63;
    int c = lane << 2;
    ushort4 x4 = *(const ushort4*)(xs + (size_t)node * HDIM + c);
    float4 as4 = *(const float4*)(att_src_l + c);
    float4 ad4 = *(const float4*)(att_dst_l + c);
    float x0 = b2f(x4.x), x1 = b2f(x4.y), x2 = b2f(x4.z), x3 = b2f(x4.w);
    float vs = x0 * as4.x + x1 * as4.y + x2 * as4.z + x3 * as4.w;
    float vd = x0 * ad4.x + x1 * ad4.y + x2 * ad4.z + x3 * ad4.w;
#pragma unroll
    for (int off = 4; off >= 1; off >>= 1) {
        vs += __shfl_down(vs, off, 8);
        vd += __shfl_down(vd, off, 8);
    }
    if ((lane & 7) == 0) {
        a_src[node * 8 + (lane >> 3)] = vs;
        a_dst[node * 8 + (lane >> 3)] = vd;
    }
}

// ---------------------------------------------------------------------------
// Fused GAT softmax+aggregate: one wave per dst node, unroll-4 edge pipeline
// ---------------------------------------------------------------------------
__global__ __launch_bounds__(256)
void gat_aggregate_kernel(const u16* __restrict__ xs, const float* __restrict__ a_src,
                          const float* __restrict__ a_dst, const u16* __restrict__ a_e_all,
                          const int* __restrict__ row_ptr, const int* __restrict__ col_src,
                          const int* __restrict__ col_eid, const float* __restrict__ bias_l,
                          u16* __restrict__ outb, int li) {
    int n = (blockIdx.x << 2) + (threadIdx.x >> 6);
    int lane = threadIdx.x & 63;
    int c = lane << 2;
    int nh = lane >> 3;
    const int aeo = li * 8 + nh;
    float adst = a_dst[n * 8 + nh];
    int s = row_ptr[n], e = row_ptr[n + 1];
    float4 acc = make_float4(0.f, 0.f, 0.f, 0.f);
    float den = 0.f;
    int p = s;
    for (; p + 4 <= e; p += 4) {
        int s0 = col_src[p],     s1 = col_src[p + 1];
        int s2 = col_src[p + 2], s3 = col_src[p + 3];
        int e0 = col_eid[p],     e1 = col_eid[p + 1];
        int e2 = col_eid[p + 2], e3 = col_eid[p + 3];
        float as0 = a_src[s0 * 8 + nh], as1 = a_src[s1 * 8 + nh];
        float as2 = a_src[s2 * 8 + nh], as3 = a_src[s3 * 8 + nh];
        float ae0 = b2f(a_e_all[(size_t)e0 * 32 + aeo]);
        float ae1 = b2f(a_e_all[(size_t)e1 * 32 + aeo]);
        float ae2 = b2f(a_e_all[(size_t)e2 * 32 + aeo]);
        float ae3 = b2f(a_e_all[(size_t)e3 * 32 + aeo]);
        ushort4 x0 = *(const ushort4*)(xs + (size_t)s0 * HDIM + c);
        ushort4 x1 = *(const ushort4*)(xs + (size_t)s1 * HDIM + c);
        ushort4 x2 = *(const ushort4*)(xs + (size_t)s2 * HDIM + c);
        ushort4 x3 = *(const ushort4*)(xs + (size_t)s3 * HDIM + c);
        float al0 = as0 + adst + ae0; al0 = (al0 > 0.f) ? al0 : 0.2f * al0;
        float al1 = as1 + adst + ae1; al1 = (al1 > 0.f) ? al1 : 0.2f * al1;
        float al2 = as2 + adst + ae2; al2 = (al2 > 0.f) ? al2 : 0.2f * al2;
        float al3 = as3 + adst + ae3; al3 = (al3 > 0.f) ? al3 : 0.2f * al3;
        float ex0 = __expf(al0), ex1 = __expf(al1);
        float ex2 = __expf(al2), ex3 = __expf(al3);
        den += (ex0 + ex1) + (ex2 + ex3);
        acc.x += ex0 * b2f(x0.x) + ex1 * b2f(x1.x) + ex2 * b2f(x2.x) + ex3 * b2f(x3.x);
        acc.y += ex0 * b2f(x0.y) + ex1 * b2f(x1.y) + ex2 * b2f(x2.y) + ex3 * b2f(x3.y);
        acc.z += ex0 * b2f(x0.z) + ex1 * b2f(x1.z) + ex2 * b2f(x2.z) + ex3 * b2f(x3.z);
        acc.w += ex0 * b2f(x0.w) + ex1 * b2f(x1.w) + ex2 * b2f(x2.w) + ex3 * b2f(x3.w);
    }
    for (; p + 2 <= e; p += 2) {
        int s0 = col_src[p],     s1 = col_src[p + 1];
        int e0 = col_eid[p],     e1 = col_eid[p + 1];
        float as0 = a_src[s0 * 8 + nh];
        float as1 = a_src[s1 * 8 + nh];
        float ae0 = b2f(a_e_all[(size_t)e0 * 32 + aeo]);
        float ae1 = b2f(a_e_all[(size_t)e1 * 32 + aeo]);
        ushort4 x0 = *(const ushort4*)(xs + (size_t)s0 * HDIM + c);
        ushort4 x1 = *(const ushort4*)(xs + (size_t)s1 * HDIM + c);
        float al0 = as0 + adst + ae0; al0 = (al0 > 0.f) ? al0 : 0.2f * al0;
        float al1 = as1 + adst + ae1; al1 = (al1 > 0.f) ? al1 : 0.2f * al1;
        float ex0 = __expf(al0);
        float ex1 = __expf(al1);
        den += ex0 + ex1;
        acc.x += ex0 * b2f(x0.x) + ex1 * b2f(x1.x);
        acc.y += ex0 * b2f(x0.y) + ex1 * b2f(x1.y);
        acc.z += ex0 * b2f(x0.z) + ex1 * b2f(x1.z);
        acc.w += ex0 * b2f(x0.w) + ex1 * b2f(x1.w);
    }
    if (p < e) {
        int s0 = col_src[p];
        int e0 = col_eid[p];
        float al = a_src[s0 * 8 + nh] + adst + b2f(a_e_all[(size_t)e0 * 32 + aeo]);
        al = (al > 0.f) ? al : 0.2f * al;
        float ex = __expf(al);
        den += ex;
        ushort4 x4 = *(const ushort4*)(xs + (size_t)s0 * HDIM + c);
        acc.x += ex * b2f(x4.x); acc.y += ex * b2f(x4.y);
        acc.z += ex * b2f(x4.z); acc.w += ex * b2f(x4.w);
    }
    float inv = 1.f / (den + 1e-16f);
    float4 b4 = *(const float4*)(bias_l + c);
    ushort4 o4;
    o4.x = f2bf(acc.x * inv + b4.x);
    o4.y = f2bf(acc.y * inv + b4.y);
    o4.z = f2bf(acc.z * inv + b4.z);
    o4.w = f2bf(acc.w * inv + b4.w);
    *(ushort4*)(outb + (size_t)n * HDIM + c) = o4;
}

// ---------------------------------------------------------------------------
// BatchNorm stats, stage 1
// ---------------------------------------------------------------------------
__global__ __launch_bounds__(256)
void bn_stats1_kernel(const u16* __restrict__ outb, float* __restrict__ gsum,
                      float* __restrict__ gsq) {
    __shared__ float lsum[8][HDIM];
    __shared__ float lsq[8][HDIM];
    const int t = threadIdx.x;
    const int b = blockIdx.x;            // 800 blocks
    const int c0 = (t & 31) * 8;
    const int g = t >> 5;
    const size_t base = (size_t)b * 64 * HDIM;
    float s[8] = {}, q[8] = {};
#pragma unroll
    for (int i = 0; i < 8; ++i) {
        const u16* p = outb + base + i * 2048 + t * 8;
        ushort4 u0 = *(const ushort4*)p;
        ushort4 u1 = *(const ushort4*)(p + 4);
        float v0 = b2f(u0.x), v1 = b2f(u0.y), v2 = b2f(u0.z), v3 = b2f(u0.w);
        float v4 = b2f(u1.x), v5 = b2f(u1.y), v6 = b2f(u1.z), v7 = b2f(u1.w);
        s[0] += v0; q[0] += v0 * v0;  s[1] += v1; q[1] += v1 * v1;
        s[2] += v2; q[2] += v2 * v2;  s[3] += v3; q[3] += v3 * v3;
        s[4] += v4; q[4] += v4 * v4;  s[5] += v5; q[5] += v5 * v5;
        s[6] += v6; q[6] += v6 * v6;  s[7] += v7; q[7] += v7 * v7;
    }
#pragma unroll
    for (int j = 0; j < 8; ++j) { lsum[g][c0 + j] = s[j]; lsq[g][c0 + j] = q[j]; }
    __syncthreads();
    float ts = 0.f, tq = 0.f;
#pragma unroll
    for (int gg = 0; gg < 8; ++gg) { ts += lsum[gg][t]; tq += lsq[gg][t]; }
    int slot = b & (BN_SLOTS - 1);
    atomicAdd(&gsum[slot * HDIM + t], ts);
    atomicAdd(&gsq[slot * HDIM + t], tq);
}

// stage 2: fold 16 slots -> mu, inv; zero slots for next layer (graph-safe)
__global__ __launch_bounds__(256)
void bn_stats2_kernel(float* __restrict__ gsum, float* __restrict__ gsq,
                      float* __restrict__ mu, float* __restrict__ inv) {
    int c = threadIdx.x;
    float s = 0.f, s2 = 0.f;
#pragma unroll
    for (int b = 0; b < BN_SLOTS; ++b) {
        s += gsum[b * HDIM + c];
        s2 += gsq[b * HDIM + c];
        gsum[b * HDIM + c] = 0.f;
        gsq[b * HDIM + c] = 0.f;
    }
    float m = s / (float)N_NODES;
    float var = s2 / (float)N_NODES - m * m;
    mu[c] = m;
    inv[c] = rsqrtf(var + 1e-5f);
}

__global__ __launch_bounds__(256)
void bn_apply_kernel(const u16* __restrict__ outb, const float* __restrict__ mu,
                     const float* __restrict__ inv, const float* __restrict__ gamma_l,
                     const float* __restrict__ beta_l, u16* __restrict__ h, int addres) {
    int idx = blockIdx.x * 256 + threadIdx.x;       // N*H/4 threads
    int c = (idx & 63) << 2;
    ushort4 v4 = *(const ushort4*)(outb + (size_t)idx * 4);
    float4 m4 = *(const float4*)(mu + c);
    float4 i4 = *(const float4*)(inv + c);
    float4 g4 = *(const float4*)(gamma_l + c);
    float4 b4 = *(const float4*)(beta_l + c);
    float v0 = fmaxf(g4.x * (b2f(v4.x) - m4.x) * i4.x + b4.x, 0.f);
    float v1 = fmaxf(g4.y * (b2f(v4.y) - m4.y) * i4.y + b4.y, 0.f);
    float v2 = fmaxf(g4.z * (b2f(v4.z) - m4.z) * i4.z + b4.z, 0.f);
    float v3 = fmaxf(g4.w * (b2f(v4.w) - m4.w) * i4.w + b4.w, 0.f);
    if (addres) {
        ushort4 h4 = *(const ushort4*)(h + (size_t)idx * 4);
        v0 += b2f(h4.x); v1 += b2f(h4.y); v2 += b2f(h4.z); v3 += b2f(h4.w);
    }
    ushort4 o4;
    o4.x = f2bf(v0); o4.y = f2bf(v1); o4.z = f2bf(v2); o4.w = f2bf(v3);
    *(ushort4*)(h + (size_t)idx * 4) = o4;
}

// ---------------------------------------------------------------------------
// MFMA MHA: one 64-thread block per (graph, head), packed qkv (stride 768).
// (round-11 verified 72-VGPR version)
// ---------------------------------------------------------------------------
__global__ __launch_bounds__(64)
void mha_attn_kernel(const u16* __restrict__ qkv, u16* __restrict__ o) {
    const int g = blockIdx.x >> 3;
    const int head = blockIdx.x & 7;
    const int l = threadIdx.x;
    __shared__ u16 VT[DHEAD][132];     // V^T: [d][key], keys zero-padded to 128
    __shared__ u16 P[16][132];         // row-tile of probabilities (bf16)
    const size_t base = (size_t)g * NPGRAPH * 768 + head * 32;

    for (int idx = l; idx < 32 * 128; idx += 64) {
        int m = idx >> 5, d = idx & 31;
        u16 v = 0;
        if (m < 100) v = qkv[base + (size_t)m * 768 + 512 + d];
        VT[d][m] = v;
    }
    bf16x8 kf[7];
#pragma unroll
    for (int n = 0; n < 7; ++n) {
        int r = n * 16 + (l & 15);
        kf[n] = *(const bf16x8*)(qkv + base + (size_t)r * 768 + 256 + ((l >> 4) << 3));
    }
    __syncthreads();
    bf16x8 vf[2][4];
#pragma unroll
    for (int dt = 0; dt < 2; ++dt)
#pragma unroll
        for (int kc = 0; kc < 4; ++kc)
            vf[dt][kc] = *(const bf16x8*)(&VT[dt * 16 + (l & 15)][kc * 32 + ((l >> 4) << 3)]);

    const float SC = 0.17677669529663687f;   // 1/sqrt(32)
    const bool c6ok = (96 + (l & 15)) < 100;

    for (int mt = 0; mt < 7; ++mt) {
        int qr = mt * 16 + (l & 15);
        bf16x8 qf = *(const bf16x8*)(qkv + base + (size_t)qr * 768 + ((l >> 4) << 3));
        f32x4 sa[7];
#pragma unroll
        for (int n = 0; n < 7; ++n) {
            f32x4 z = {0.f, 0.f, 0.f, 0.f};
            sa[n] = __builtin_amdgcn_mfma_f32_16x16x32_bf16(qf, kf[n], z, 0, 0, 0);
        }
        float linv[4];
#pragma unroll
        for (int j = 0; j < 4; ++j) {
            float m = -1e30f;
#pragma unroll
            for (int n = 0; n < 6; ++n) m = fmaxf(m, sa[n][j]);
            if (c6ok) m = fmaxf(m, sa[6][j]);
            m *= SC;
#pragma unroll
            for (int off = 1; off < 16; off <<= 1) m = fmaxf(m, __shfl_xor(m, off));
            float ls = 0.f;
            float pv[7];
#pragma unroll
            for (int n = 0; n < 7; ++n) {
                float p_ = 0.f;
                if (n < 6 || c6ok) p_ = __expf(SC * sa[n][j] - m);
                pv[n] = p_;
                ls += p_;
            }
#pragma unroll
            for (int off = 1; off < 16; off <<= 1) ls += __shfl_xor(ls, off);
            linv[j] = 1.f / ls;
            int rt = ((l >> 4) << 2) + j;
#pragma unroll
            for (int n = 0; n < 7; ++n) P[rt][n * 16 + (l & 15)] = f2bf(pv[n]);
            P[rt][112 + (l & 15)] = 0;
        }
        __syncthreads();
        f32x4 oa[2] = {};
#pragma unroll
        for (int kc = 0; kc < 4; ++kc) {
            bf16x8 pf = *(const bf16x8*)(&P[l & 15][kc * 32 + ((l >> 4) << 3)]);
            oa[0] = __builtin_amdgcn_mfma_f32_16x16x32_bf16(pf, vf[0][kc], oa[0], 0, 0, 0);
            oa[1] = __builtin_amdgcn_mfma_f32_16x16x32_bf16(pf, vf[1][kc], oa[1], 0, 0, 0);
        }
        int r0 = mt * 16 + ((l >> 4) << 2);
#pragma unroll
        for (int dt = 0; dt < 2; ++dt)
#pragma unroll
            for (int j = 0; j < 4; ++j) {
                int r = r0 + j;
                if (r < 100)
                    o[(size_t)(g * NPGRAPH + r) * HDIM + head * 32 + dt * 16 + (l & 15)] =
                        f2bf(oa[dt][j] * linv[j]);
            }
        __syncthreads();
    }
}

// mean pool over nodes per graph
__global__ __launch_bounds__(256)
void pool_kernel(const u16* __restrict__ o2, u16* __restrict__ pooled) {
    int g = blockIdx.x;
    int c = threadIdx.x;
    float s = 0.f;
    for (int r = 0; r < NPGRAPH; ++r) s += b2f(o2[((size_t)g * NPGRAPH + r) * HDIM + c]);
    pooled[g * HDIM + c] = f2bf(s * 0.01f);
}

// task heads
__global__ __launch_bounds__(64)
void heads_kernel(const u16* __restrict__ s2, const float* __restrict__ w1,
                  const float* __restrict__ b1, const float* __restrict__ w2,
                  const float* __restrict__ b2, float* __restrict__ out) {
    int g = blockIdx.x / TASKS;
    int tt = blockIdx.x % TASKS;
    int d = threadIdx.x;   // 64
    float s = b1[tt * 64 + d];
    const u16* srow = s2 + (size_t)g * 128;
    const float* wcol = w1 + (size_t)tt * 128 * 64 + d;
    for (int k = 0; k < 128; ++k) s += b2f(srow[k]) * wcol[k * 64];
    s = fmaxf(s, 0.f);
    float v = s * w2[tt * 64 + d];
#pragma unroll
    for (int off = 32; off >= 1; off >>= 1) v += __shfl_down(v, off);
    if (d == 0) out[g * TASKS + tt] = v + b2[tt];
}

// ---------------------------------------------------------------------------
extern "C" void kernel_launch(void* const* d_in, const int* in_sizes, int n_in,
                              void* d_out, int out_size, void* d_ws, size_t ws_size,
                              hipStream_t stream) {
    const float* x          = (const float*)d_in[0];
    const float* edge_attr  = (const float*)d_in[1];
    const int*   edge_index = (const int*)d_in[2];
    const float* atom_w     = (const float*)d_in[4];
    const float* atom_b     = (const float*)d_in[5];
    const float* edge_w     = (const float*)d_in[6];
    const float* edge_b     = (const float*)d_in[7];
    const float* gat_lin_w  = (const float*)d_in[8];
    const float* gat_lin_ew = (const float*)d_in[9];
    const float* att_src    = (const float*)d_in[10];
    const float* att_dst    = (const float*)d_in[11];
    const float* att_edge   = (const float*)d_in[12];
    const float* gat_bias   = (const float*)d_in[13];
    const float* bn_gamma   = (const float*)d_in[14];
    const float* bn_beta    = (const float*)d_in[15];
    const float* mha_in_w   = (const float*)d_in[16];
    const float* mha_in_b   = (const float*)d_in[17];
    const float* mha_out_w  = (const float*)d_in[18];
    const float* mha_out_b  = (const float*)d_in[19];
    const float* sh_w1      = (const float*)d_in[20];
    const float* sh_b1      = (const float*)d_in[21];
    const float* sh_w2      = (const float*)d_in[22];
    const float* sh_b2      = (const float*)d_in[23];
    const float* head_w1    = (const float*)d_in[24];
    const float* head_b1    = (const float*)d_in[25];
    const float* head_w2    = (const float*)d_in[26];
    const float* head_b2    = (const float*)d_in[27];
    float* out = (float*)d_out;

    const int* src = edge_index;
    const int* dst = edge_index + N_EDGES;

    // ---- workspace layout (bytes, 256B aligned; ~112 MB) ----
    size_t off = 0;
    auto alloc = [&](size_t bytes) -> void* {
        void* p = (char*)d_ws + off;
        off += (bytes + 255) & ~(size_t)255;
        return p;
    };
    const size_t NHB = (size_t)N_NODES * HDIM * sizeof(u16);      // 26,214,400
    u16* h_buf = (u16*)alloc(NHB);
    char* region1 = (char*)alloc((size_t)N_NODES * 768 * sizeof(u16));   // 78.6MB
    u16* xs_buf  = (u16*)region1;
    u16* out_buf = (u16*)(region1 + NHB);
    u16* a_e_all = (u16*)(region1 + 2 * NHB);
    u16* qkv_buf = (u16*)region1;     // phase2: xs/outb/a_e dead
    u16* o2_buf  = (u16*)region1;     // phase3: qkv dead after attention
    u16* o_buf   = h_buf;             // h dead after qkv GEMM
    u16* x_bf    = out_buf;           // alias: dead before aggregate
    float* a_src_b = (float*)alloc((size_t)N_NODES * 8 * sizeof(float));
    float* a_dst_b = (float*)alloc((size_t)N_NODES * 8 * sizeof(float));
    float* gsum    = (float*)alloc(BN_SLOTS * HDIM * sizeof(float));
    float* gsq     = (float*)alloc(BN_SLOTS * HDIM * sizeof(float));
    float* mu_b    = (float*)alloc(HDIM * sizeof(float));
    float* inv_b   = (float*)alloc(HDIM * sizeof(float));
    float* P_e     = (float*)alloc(LAYERS * HDIM * 8 * sizeof(float));
    float* Qm      = (float*)alloc(256 * sizeof(float));
    float* c0m     = (float*)alloc(32 * sizeof(float));
    u16* atom_wt   = (u16*)alloc((size_t)HDIM * FATOM * sizeof(u16));
    u16* lin_wt    = (u16*)alloc((size_t)LAYERS * HDIM * HDIM * sizeof(u16));
    u16* in_w_bf   = (u16*)alloc((size_t)768 * HDIM * sizeof(u16));
    u16* out_w_bf  = (u16*)alloc((size_t)HDIM * HDIM * sizeof(u16));
    u16* sh1_t     = (u16*)alloc((size_t)HDIM * HDIM * sizeof(u16));
    u16* sh2_t     = (u16*)alloc((size_t)128 * HDIM * sizeof(u16));
    u16* pooled    = (u16*)alloc((size_t)GRAPHS * HDIM * sizeof(u16));
    u16* s1_b      = (u16*)alloc((size_t)GRAPHS * HDIM * sizeof(u16));
    u16* s2_b      = (u16*)alloc((size_t)GRAPHS * 128 * sizeof(u16));
    int* deg       = (int*)alloc(N_NODES * sizeof(int));
    int* row_ptr   = (int*)alloc((N_NODES + 256) * sizeof(int));
    int* cursor    = (int*)alloc(N_NODES * sizeof(int));
    int* col_src   = (int*)alloc(NFULL * sizeof(int));
    int* col_eid   = (int*)alloc(NFULL * sizeof(int));
    int* bsum      = (int*)alloc(64 * sizeof(int));
    (void)ws_size; (void)in_sizes; (void)n_in; (void)out_size;

    // ---- weight + input bf16 conversion ----
    convert_t_kernel<<<(HDIM * FATOM + 255) / 256, 256, 0, stream>>>(atom_w, atom_wt, FATOM, HDIM);
    convert_t4_kernel<<<(LAYERS * HDIM * HDIM) / 256, 256, 0, stream>>>(gat_lin_w, lin_wt);
    convert_kernel<<<(768 * HDIM + 255) / 256, 256, 0, stream>>>(mha_in_w, in_w_bf, 768 * HDIM);
    convert_kernel<<<(HDIM * HDIM + 255) / 256, 256, 0, stream>>>(mha_out_w, out_w_bf, HDIM * HDIM);
    convert_t_kernel<<<(HDIM * HDIM + 255) / 256, 256, 0, stream>>>(sh_w1, sh1_t, HDIM, HDIM);
    convert_t_kernel<<<(HDIM * 128 + 255) / 256, 256, 0, stream>>>(sh_w2, sh2_t, HDIM, 128);
    convert_kernel<<<(N_NODES * FATOM + 255) / 256, 256, 0, stream>>>(x, x_bf, N_NODES * FATOM);

    // ---- CSR (3-stage scan) ----
    hipMemsetAsync(deg, 0, N_NODES * sizeof(int), stream);
    edge_hist_kernel<<<(N_EDGES + 255) / 256, 256, 0, stream>>>(dst, deg);
    scan1_kernel<<<SCAN_BLOCKS, 1024, 0, stream>>>(deg, row_ptr, bsum);
    scan2_kernel<<<1, 64, 0, stream>>>(bsum, row_ptr);
    scan3_kernel<<<N_NODES / 256, 256, 0, stream>>>(row_ptr, bsum);
    selfloop_init_kernel<<<(N_NODES + 255) / 256, 256, 0, stream>>>(row_ptr, cursor, col_src, col_eid);
    scatter_kernel<<<(N_EDGES + 255) / 256, 256, 0, stream>>>(src, dst, cursor, col_src, col_eid);

    // ---- attention-logit edge projections ----
    proj_pe_kernel<<<32, 256, 0, stream>>>(gat_lin_ew, att_edge, P_e);
    proj_q_kernel<<<1, 256, 0, stream>>>(edge_w, edge_b, P_e, Qm, c0m);
    ae_real_kernel<<<N_EDGES / 8, 256, 0, stream>>>(edge_attr, Qm, c0m, a_e_all);
    ae_self_kernel<<<N_NODES / 8, 256, 0, stream>>>(
        edge_attr, row_ptr, col_eid, Qm, c0m, a_e_all);

    // ---- atom encoder ----
    gemm_mfma_kernel<true, false><<<(HDIM / 128) * (N_NODES / 128), 256, 0, stream>>>(
        x_bf, atom_wt, atom_b, h_buf, N_NODES, FATOM, HDIM);

    // ---- GAT layers ----
    hipMemsetAsync(gsum, 0, BN_SLOTS * HDIM * sizeof(float), stream);
    hipMemsetAsync(gsq, 0, BN_SLOTS * HDIM * sizeof(float), stream);
    for (int li = 0; li < LAYERS; ++li) {
        gemm_mfma_kernel<false, false><<<(HDIM / 128) * (N_NODES / 128), 256, 0, stream>>>(
            h_buf, lin_wt + (size_t)li * HDIM * HDIM, nullptr, xs_buf, N_NODES, HDIM, HDIM);
        gat_asd_kernel<<<N_NODES / 4, 256, 0, stream>>>(
            xs_buf, att_src + li * HDIM, att_dst + li * HDIM, a_src_b, a_dst_b);
        gat_aggregate_kernel<<<N_NODES / 4, 256, 0, stream>>>(
            xs_buf, a_src_b, a_dst_b, a_e_all, row_ptr, col_src, col_eid,
            gat_bias + li * HDIM, out_buf, li);
        bn_stats1_kernel<<<N_NODES / 64, 256, 0, stream>>>(out_buf, gsum, gsq);
        bn_stats2_kernel<<<1, 256, 0, stream>>>(gsum, gsq, mu_b, inv_b);
        bn_apply_kernel<<<(N_NODES * HDIM / 4) / 256, 256, 0, stream>>>(
            out_buf, mu_b, inv_b, bn_gamma + li * HDIM, bn_beta + li * HDIM, h_buf, li > 0 ? 1 : 0);
    }

    // ---- MHA (combined qkv GEMM + 64-thread attention) ----
    gemm_mfma_kernel<true, false><<<(768 / 128) * (N_NODES / 128), 256, 0, stream>>>(
        h_buf, in_w_bf, mha_in_b, qkv_buf, N_NODES, HDIM, 768);
    mha_attn_kernel<<<GRAPHS * NHEADS, 64, 0, stream>>>(qkv_buf, o_buf);
    gemm_mfma_kernel<true, false><<<(HDIM / 128) * (N_NODES / 128), 256, 0, stream>>>(
        o_buf, out_w_bf, mha_out_b, o2_buf, N_NODES, HDIM, HDIM);
    pool_kernel<<<GRAPHS, 256, 0, stream>>>(o2_buf, pooled);

    // ---- shared MLP + task heads ----
    gemm_mfma_kernel<true, true><<<(HDIM / 128) * (GRAPHS / 128), 256, 0, stream>>>(
        pooled, sh1_t, sh_b1, s1_b, GRAPHS, HDIM, HDIM);
    gemm_mfma_kernel<true, true><<<(128 / 128) * (GRAPHS / 128), 256, 0, stream>>>(
        s1_b, sh2_t, sh_b2, s2_b, GRAPHS, HDIM, 128);
    heads_kernel<<<GRAPHS * TASKS, 64, 0, stream>>>(
        s2_b, head_w1, head_b1, head_w2, head_b2, out);
}

// Round 16
// 870.045 us; speedup vs baseline: 1.0555x; 1.0011x over previous
//
#include <hip/hip_runtime.h>
#include <hip/hip_bf16.h>

#define N_NODES 51200
#define N_EDGES 300000
#define NFULL   351200   // E + N
#define GRAPHS  512
#define NPGRAPH 100
#define FATOM   64
#define FEDGE   8
#define HDIM    256
#define NHEADS  8
#define DHEAD   32
#define LAYERS  4
#define TASKS   5
#define BN_SLOTS 16
#define SCAN_BLOCKS 50   // 50 * 1024 = 51200

typedef unsigned short u16;
typedef __attribute__((ext_vector_type(8))) short bf16x8;
typedef __attribute__((ext_vector_type(4))) float f32x4;

__device__ __forceinline__ float b2f(u16 u) {
    return __uint_as_float(((unsigned)u) << 16);
}
__device__ __forceinline__ u16 f2bf(float f) {
    unsigned u = __float_as_uint(f);
    unsigned r = u + 0x7fffu + ((u >> 16) & 1u);   // round-to-nearest-even
    return (u16)(r >> 16);
}

// ---------------------------------------------------------------------------
// fp32 -> bf16 flat convert
// ---------------------------------------------------------------------------
__global__ __launch_bounds__(256)
void convert_kernel(const float* __restrict__ in, u16* __restrict__ out, int n) {
    int i = blockIdx.x * 256 + threadIdx.x;
    if (i < n) out[i] = f2bf(in[i]);
}

// fp32 [R][C] -> bf16 [C][R]
__global__ __launch_bounds__(256)
void convert_t_kernel(const float* __restrict__ in, u16* __restrict__ out, int R, int C) {
    int idx = blockIdx.x * 256 + threadIdx.x;
    if (idx >= R * C) return;
    int c = idx / R, r = idx % R;
    out[idx] = f2bf(in[(size_t)r * C + c]);
}

// 4 layers of [256][256] transposed in one launch
__global__ __launch_bounds__(256)
void convert_t4_kernel(const float* __restrict__ in, u16* __restrict__ out) {
    int idx = blockIdx.x * 256 + threadIdx.x;   // 4*65536
    int li = idx >> 16, rem = idx & 65535;
    int c = rem >> 8, r = rem & 255;
    out[idx] = f2bf(in[(size_t)li * 65536 + r * 256 + c]);
}

// ---------------------------------------------------------------------------
// MFMA bf16 GEMM (round-11 verified): BM=BN=128, BK=64, 4 waves 2x2,
// XCD chunk swizzle, LDS epilogue -> coalesced 16B stores.
// QKV: route the C store into three stride-256 buffers laid out
// [3][M][256] at C (mat = bn/256, col = bn%256) - single A pass, narrow-N
// write layout (tests stride-determined write-amplification hypothesis).
// ---------------------------------------------------------------------------
template<bool BIAS, bool RELU, bool QKV>
__global__ __launch_bounds__(256, 2)
void gemm_mfma_kernel(const u16* __restrict__ A, const u16* __restrict__ Bt,
                      const float* __restrict__ bias, u16* __restrict__ C,
                      int M, int K, int N) {
    __shared__ u16 smem[136 * 128];
    u16* As = smem;                          // [128][64]
    u16* Bs = smem + 128 * 64;               // [128][64]
    const int t = threadIdx.x;
    const int lane = t & 63;
    const int w = t >> 6;
    const int wr = w >> 1, wc = w & 1;

    const int nwg = (int)gridDim.x;
    const int bid = (int)blockIdx.x;
    const int q = nwg >> 3, r = nwg & 7;
    const int xcd = bid & 7, idx0 = bid >> 3;
    const int wgid = (xcd < r) ? xcd * (q + 1) + idx0
                               : r * (q + 1) + (xcd - r) * q + idx0;
    const int nx = N >> 7;
    const int bn = (wgid % nx) * 128;
    const int bm = (wgid / nx) * 128;

    f32x4 acc[4][4] = {};

    for (int kt = 0; kt < K; kt += 64) {
        uint4 ra[4], rb[4];
#pragma unroll
        for (int i = 0; i < 4; ++i) {
            int idx = i * 256 + t;
            int row = idx >> 3, ch = idx & 7;
            ra[i] = *(const uint4*)(A + (size_t)(bm + row) * K + kt + ch * 8);
            rb[i] = *(const uint4*)(Bt + (size_t)(bn + row) * K + kt + ch * 8);
        }
        __syncthreads();
#pragma unroll
        for (int i = 0; i < 4; ++i) {
            int idx = i * 256 + t;
            int row = idx >> 3, ch = idx & 7;
            int sw = ch ^ (row & 7);
            *(uint4*)((char*)As + row * 128 + sw * 16) = ra[i];
            *(uint4*)((char*)Bs + row * 128 + sw * 16) = rb[i];
        }
        __syncthreads();
#pragma unroll
        for (int kk = 0; kk < 2; ++kk) {
            bf16x8 af[4], bf[4];
#pragma unroll
            for (int m = 0; m < 4; ++m) {
                int rr = wr * 64 + m * 16 + (lane & 15);
                int ch = kk * 4 + (lane >> 4);
                af[m] = *(const bf16x8*)((const char*)As + rr * 128 + ((ch ^ (rr & 7)) << 4));
            }
#pragma unroll
            for (int n = 0; n < 4; ++n) {
                int rr = wc * 64 + n * 16 + (lane & 15);
                int ch = kk * 4 + (lane >> 4);
                bf[n] = *(const bf16x8*)((const char*)Bs + rr * 128 + ((ch ^ (rr & 7)) << 4));
            }
#pragma unroll
            for (int m = 0; m < 4; ++m)
#pragma unroll
                for (int n = 0; n < 4; ++n)
                    acc[m][n] = __builtin_amdgcn_mfma_f32_16x16x32_bf16(
                        af[m], bf[n], acc[m][n], 0, 0, 0);
        }
    }
    __syncthreads();
#pragma unroll
    for (int m = 0; m < 4; ++m)
#pragma unroll
        for (int n = 0; n < 4; ++n) {
            int coll = wc * 64 + n * 16 + (lane & 15);
            float bv = BIAS ? bias[bn + coll] : 0.f;
#pragma unroll
            for (int j = 0; j < 4; ++j) {
                float v = acc[m][n][j] + bv;
                if (RELU) v = fmaxf(v, 0.f);
                int rowl = wr * 64 + m * 16 + (lane >> 4) * 4 + j;
                smem[rowl * 136 + coll] = f2bf(v);
            }
        }
    __syncthreads();
    if (QKV) {
        const int mat = bn >> 8;           // 0,1,2
        const int cb  = bn & 255;          // 0 or 128
        u16* Cm = C + (size_t)mat * M * 256;
#pragma unroll
        for (int p = 0; p < 8; ++p) {
            int rowl = p * 16 + (t >> 4);
            uint4 v = *(const uint4*)(smem + rowl * 136 + (t & 15) * 8);
            *(uint4*)(Cm + (size_t)(bm + rowl) * 256 + cb + (t & 15) * 8) = v;
        }
    } else {
#pragma unroll
        for (int p = 0; p < 8; ++p) {
            int rowl = p * 16 + (t >> 4);
            uint4 v = *(const uint4*)(smem + rowl * 136 + (t & 15) * 8);
            *(uint4*)(C + (size_t)(bm + rowl) * N + bn + (t & 15) * 8) = v;
        }
    }
}

// ---------------------------------------------------------------------------
// Degree histogram (int atomics)
// ---------------------------------------------------------------------------
__global__ __launch_bounds__(256)
void edge_hist_kernel(const int* __restrict__ dst, int* __restrict__ deg) {
    int e = blockIdx.x * 256 + threadIdx.x;
    if (e >= N_EDGES) return;
    atomicAdd(&deg[dst[e]], 1);
}

// ---------------------------------------------------------------------------
// Three-stage exclusive scan of (deg[i]+1) -> row_ptr[0..N]
// ---------------------------------------------------------------------------
__global__ __launch_bounds__(1024)
void scan1_kernel(const int* __restrict__ deg, int* __restrict__ row_ptr,
                  int* __restrict__ bsum) {
    __shared__ int buf[1024];
    const int b = blockIdx.x, t = threadIdx.x;
    const int i = b * 1024 + t;
    int v = deg[i] + 1;
    buf[t] = v;
    __syncthreads();
    for (int off = 1; off < 1024; off <<= 1) {
        int x = (t >= off) ? buf[t - off] : 0;
        __syncthreads();
        buf[t] += x;
        __syncthreads();
    }
    row_ptr[i] = buf[t] - v;               // exclusive within block
    if (t == 1023) bsum[b] = buf[t];
}

__global__ __launch_bounds__(64)
void scan2_kernel(int* __restrict__ bsum, int* __restrict__ row_ptr) {
    int t = threadIdx.x;                   // one wave
    int orig = (t < SCAN_BLOCKS) ? bsum[t] : 0;
    int v = orig;
    for (int off = 1; off < 64; off <<= 1) {
        int x = __shfl_up(v, off);
        if (t >= off) v += x;
    }
    if (t < SCAN_BLOCKS) bsum[t] = v - orig;   // exclusive block offset
    if (t == SCAN_BLOCKS - 1) row_ptr[N_NODES] = v;
}

__global__ __launch_bounds__(256)
void scan3_kernel(int* __restrict__ row_ptr, const int* __restrict__ bsum) {
    int i = blockIdx.x * 256 + threadIdx.x;
    if (i >= N_NODES) return;
    row_ptr[i] += bsum[i >> 10];
}

__global__ __launch_bounds__(256)
void selfloop_init_kernel(const int* __restrict__ row_ptr, int* __restrict__ cursor,
                          int* __restrict__ col_src, int* __restrict__ col_eid) {
    int n = blockIdx.x * 256 + threadIdx.x;
    if (n >= N_NODES) return;
    cursor[n] = row_ptr[n];
    int pos = row_ptr[n + 1] - 1;
    col_src[pos] = n;
    col_eid[pos] = N_EDGES + n;
}

__global__ __launch_bounds__(256)
void scatter_kernel(const int* __restrict__ src, const int* __restrict__ dst,
                    int* __restrict__ cursor, int* __restrict__ col_src,
                    int* __restrict__ col_eid) {
    int e = blockIdx.x * 256 + threadIdx.x;
    if (e >= N_EDGES) return;
    int d = dst[e];
    int pos = atomicAdd(&cursor[d], 1);
    col_src[pos] = src[e];
    col_eid[pos] = e;
}

// ---------------------------------------------------------------------------
// P_e[li][k][nh] = sum_d lin_edge_w[li][k][nh*32+d] * att_edge[li][nh][d]
// ---------------------------------------------------------------------------
__global__ __launch_bounds__(256)
void proj_pe_kernel(const float* __restrict__ lin_edge_w, const float* __restrict__ att_edge,
                    float* __restrict__ P_e) {
    int idx = blockIdx.x * 256 + threadIdx.x;   // 4*256*8 = 8192
    int li = idx >> 11;
    int rem = idx & 2047;
    int k = rem >> 3, nh = rem & 7;
    const float* w = lin_edge_w + (size_t)li * HDIM * HDIM + (size_t)k * HDIM + nh * DHEAD;
    const float* a = att_edge + li * HDIM + nh * DHEAD;
    float s = 0.f;
#pragma unroll
    for (int d = 0; d < DHEAD; ++d) s += w[d] * a[d];
    P_e[idx] = s;
}

// Qm[li][f][nh] = sum_k edge_w[f][k] * P_e[li][k][nh];  c0[li][nh] = edge_b @ P_e
__global__ __launch_bounds__(256)
void proj_q_kernel(const float* __restrict__ edge_w, const float* __restrict__ edge_b,
                   const float* __restrict__ P_e, float* __restrict__ Qm,
                   float* __restrict__ c0m) {
    int t = threadIdx.x;          // 256 = 4*8*8
    int li = t >> 6, f = (t >> 3) & 7, nh = t & 7;
    const float* pe = P_e + li * 2048;
    float q = 0.f;
    for (int k = 0; k < HDIM; ++k) q += edge_w[f * HDIM + k] * pe[k * 8 + nh];
    Qm[t] = q;
    if (t < 32) {
        int li2 = t >> 3, nh2 = t & 7;
        const float* pe2 = P_e + li2 * 2048;
        float c = 0.f;
        for (int k = 0; k < HDIM; ++k) c += edge_b[k] * pe2[k * 8 + nh2];
        c0m[t] = c;
    }
}

// a_e for real edges: [E,32] bf16 ; 8 edges x 32 outputs per block
__global__ __launch_bounds__(256)
void ae_real_kernel(const float* __restrict__ edge_attr, const float* __restrict__ Qm,
                    const float* __restrict__ c0m, u16* __restrict__ a_e_all) {
    __shared__ float ea_s[8][8];
    __shared__ float Qs[256];
    __shared__ float c0s[32];
    const int t = threadIdx.x;
    const int e0 = blockIdx.x * 8;
    if (t < 64) ea_s[t >> 3][t & 7] = edge_attr[(size_t)e0 * 8 + t];
    Qs[t] = Qm[t];
    if (t < 32) c0s[t] = c0m[t];
    __syncthreads();
    int el = t >> 5, o = t & 31;
    int li = o >> 3, nh = o & 7;
    float v = c0s[o];
#pragma unroll
    for (int f = 0; f < 8; ++f) v += ea_s[el][f] * Qs[li * 64 + f * 8 + nh];
    a_e_all[(size_t)(e0 + el) * 32 + o] = f2bf(v);
}

// a_e for self loops (rows E..E+N-1): per-node edge-attr sums via CSR walk
__global__ __launch_bounds__(256)
void ae_self_kernel(const float* __restrict__ edge_attr, const int* __restrict__ row_ptr,
                    const int* __restrict__ col_eid, const float* __restrict__ Qm,
                    const float* __restrict__ c0m, u16* __restrict__ a_e_all) {
    __shared__ float ea_s[8][8];
    __shared__ int deg_s[8];
    __shared__ float Qs[256];
    __shared__ float c0s[32];
    const int t = threadIdx.x;
    const int n0 = blockIdx.x * 8;
    Qs[t] = Qm[t];
    if (t < 32) c0s[t] = c0m[t];
    if (t < 64) {
        int el = t >> 3, f = t & 7;
        int n = n0 + el;
        int s = row_ptr[n], e = row_ptr[n + 1] - 1;   // exclude self-loop slot
        float acc = 0.f;
        for (int p = s; p < e; ++p)
            acc += edge_attr[(size_t)col_eid[p] * FEDGE + f];
        ea_s[el][f] = acc;
        if (f == 0) deg_s[el] = e - s;
    }
    __syncthreads();
    int el = t >> 5, o = t & 31;
    int li = o >> 3, nh = o & 7;
    int dg = deg_s[el];
    float v = 0.f;
    if (dg > 0) {
        float invd = 1.f / (float)dg;
        v = c0s[o];
#pragma unroll
        for (int f = 0; f < 8; ++f) v += ea_s[el][f] * invd * Qs[li * 64 + f * 8 + nh];
    }
    a_e_all[(size_t)(N_EDGES + n0 + el) * 32 + o] = f2bf(v);
}

// ---------------------------------------------------------------------------
// a_src / a_dst from xs(bf16 ws): one wave per node
// ---------------------------------------------------------------------------
__global__ __launch_bounds__(256)
void gat_asd_kernel(const u16* __restrict__ xs, const float* __restrict__ att_src_l,
                    const float* __restrict__ att_dst_l, float* __restrict__ a_src,
                    float* __restrict__ a_dst) {
    int node = (blockIdx.x << 2) + (threadIdx.x >> 6);
    int lane = threadIdx.x & 63;
    int c = lane << 2;
    ushort4 x4 = *(const ushort4*)(xs + (size_t)node * HDIM + c);
    float4 as4 = *(const float4*)(att_src_l + c);
    float4 ad4 = *(const float4*)(att_dst_l + c);
    float x0 = b2f(x4.x), x1 = b2f(x4.y), x2 = b2f(x4.z), x3 = b2f(x4.w);
    float vs = x0 * as4.x + x1 * as4.y + x2 * as4.z + x3 * as4.w;
    float vd = x0 * ad4.x + x1 * ad4.y + x2 * ad4.z + x3 * ad4.w;
#pragma unroll
    for (int off = 4; off >= 1; off >>= 1) {
        vs += __shfl_down(vs, off, 8);
        vd += __shfl_down(vd, off, 8);
    }
    if ((lane & 7) == 0) {
        a_src[node * 8 + (lane >> 3)] = vs;
        a_dst[node * 8 + (lane >> 3)] = vd;
    }
}

// ---------------------------------------------------------------------------
// Fused GAT softmax+aggregate: one wave per dst node, unroll-4 edge pipeline
// ---------------------------------------------------------------------------
__global__ __launch_bounds__(256)
void gat_aggregate_kernel(const u16* __restrict__ xs, const float* __restrict__ a_src,
                          const float* __restrict__ a_dst, const u16* __restrict__ a_e_all,
                          const int* __restrict__ row_ptr, const int* __restrict__ col_src,
                          const int* __restrict__ col_eid, const float* __restrict__ bias_l,
                          u16* __restrict__ outb, int li) {
    int n = (blockIdx.x << 2) + (threadIdx.x >> 6);
    int lane = threadIdx.x & 63;
    int c = lane << 2;
    int nh = lane >> 3;
    const int aeo = li * 8 + nh;
    float adst = a_dst[n * 8 + nh];
    int s = row_ptr[n], e = row_ptr[n + 1];
    float4 acc = make_float4(0.f, 0.f, 0.f, 0.f);
    float den = 0.f;
    int p = s;
    for (; p + 4 <= e; p += 4) {
        int s0 = col_src[p],     s1 = col_src[p + 1];
        int s2 = col_src[p + 2], s3 = col_src[p + 3];
        int e0 = col_eid[p],     e1 = col_eid[p + 1];
        int e2 = col_eid[p + 2], e3 = col_eid[p + 3];
        float as0 = a_src[s0 * 8 + nh], as1 = a_src[s1 * 8 + nh];
        float as2 = a_src[s2 * 8 + nh], as3 = a_src[s3 * 8 + nh];
        float ae0 = b2f(a_e_all[(size_t)e0 * 32 + aeo]);
        float ae1 = b2f(a_e_all[(size_t)e1 * 32 + aeo]);
        float ae2 = b2f(a_e_all[(size_t)e2 * 32 + aeo]);
        float ae3 = b2f(a_e_all[(size_t)e3 * 32 + aeo]);
        ushort4 x0 = *(const ushort4*)(xs + (size_t)s0 * HDIM + c);
        ushort4 x1 = *(const ushort4*)(xs + (size_t)s1 * HDIM + c);
        ushort4 x2 = *(const ushort4*)(xs + (size_t)s2 * HDIM + c);
        ushort4 x3 = *(const ushort4*)(xs + (size_t)s3 * HDIM + c);
        float al0 = as0 + adst + ae0; al0 = (al0 > 0.f) ? al0 : 0.2f * al0;
        float al1 = as1 + adst + ae1; al1 = (al1 > 0.f) ? al1 : 0.2f * al1;
        float al2 = as2 + adst + ae2; al2 = (al2 > 0.f) ? al2 : 0.2f * al2;
        float al3 = as3 + adst + ae3; al3 = (al3 > 0.f) ? al3 : 0.2f * al3;
        float ex0 = __expf(al0), ex1 = __expf(al1);
        float ex2 = __expf(al2), ex3 = __expf(al3);
        den += (ex0 + ex1) + (ex2 + ex3);
        acc.x += ex0 * b2f(x0.x) + ex1 * b2f(x1.x) + ex2 * b2f(x2.x) + ex3 * b2f(x3.x);
        acc.y += ex0 * b2f(x0.y) + ex1 * b2f(x1.y) + ex2 * b2f(x2.y) + ex3 * b2f(x3.y);
        acc.z += ex0 * b2f(x0.z) + ex1 * b2f(x1.z) + ex2 * b2f(x2.z) + ex3 * b2f(x3.z);
        acc.w += ex0 * b2f(x0.w) + ex1 * b2f(x1.w) + ex2 * b2f(x2.w) + ex3 * b2f(x3.w);
    }
    for (; p + 2 <= e; p += 2) {
        int s0 = col_src[p],     s1 = col_src[p + 1];
        int e0 = col_eid[p],     e1 = col_eid[p + 1];
        float as0 = a_src[s0 * 8 + nh];
        float as1 = a_src[s1 * 8 + nh];
        float ae0 = b2f(a_e_all[(size_t)e0 * 32 + aeo]);
        float ae1 = b2f(a_e_all[(size_t)e1 * 32 + aeo]);
        ushort4 x0 = *(const ushort4*)(xs + (size_t)s0 * HDIM + c);
        ushort4 x1 = *(const ushort4*)(xs + (size_t)s1 * HDIM + c);
        float al0 = as0 + adst + ae0; al0 = (al0 > 0.f) ? al0 : 0.2f * al0;
        float al1 = as1 + adst + ae1; al1 = (al1 > 0.f) ? al1 : 0.2f * al1;
        float ex0 = __expf(al0);
        float ex1 = __expf(al1);
        den += ex0 + ex1;
        acc.x += ex0 * b2f(x0.x) + ex1 * b2f(x1.x);
        acc.y += ex0 * b2f(x0.y) + ex1 * b2f(x1.y);
        acc.z += ex0 * b2f(x0.z) + ex1 * b2f(x1.z);
        acc.w += ex0 * b2f(x0.w) + ex1 * b2f(x1.w);
    }
    if (p < e) {
        int s0 = col_src[p];
        int e0 = col_eid[p];
        float al = a_src[s0 * 8 + nh] + adst + b2f(a_e_all[(size_t)e0 * 32 + aeo]);
        al = (al > 0.f) ? al : 0.2f * al;
        float ex = __expf(al);
        den += ex;
        ushort4 x4 = *(const ushort4*)(xs + (size_t)s0 * HDIM + c);
        acc.x += ex * b2f(x4.x); acc.y += ex * b2f(x4.y);
        acc.z += ex * b2f(x4.z); acc.w += ex * b2f(x4.w);
    }
    float inv = 1.f / (den + 1e-16f);
    float4 b4 = *(const float4*)(bias_l + c);
    ushort4 o4;
    o4.x = f2bf(acc.x * inv + b4.x);
    o4.y = f2bf(acc.y * inv + b4.y);
    o4.z = f2bf(acc.z * inv + b4.z);
    o4.w = f2bf(acc.w * inv + b4.w);
    *(ushort4*)(outb + (size_t)n * HDIM + c) = o4;
}

// ---------------------------------------------------------------------------
// BatchNorm stats, stage 1
// ---------------------------------------------------------------------------
__global__ __launch_bounds__(256)
void bn_stats1_kernel(const u16* __restrict__ outb, float* __restrict__ gsum,
                      float* __restrict__ gsq) {
    __shared__ float lsum[8][HDIM];
    __shared__ float lsq[8][HDIM];
    const int t = threadIdx.x;
    const int b = blockIdx.x;            // 800 blocks
    const int c0 = (t & 31) * 8;
    const int g = t >> 5;
    const size_t base = (size_t)b * 64 * HDIM;
    float s[8] = {}, q[8] = {};
#pragma unroll
    for (int i = 0; i < 8; ++i) {
        const u16* p = outb + base + i * 2048 + t * 8;
        ushort4 u0 = *(const ushort4*)p;
        ushort4 u1 = *(const ushort4*)(p + 4);
        float v0 = b2f(u0.x), v1 = b2f(u0.y), v2 = b2f(u0.z), v3 = b2f(u0.w);
        float v4 = b2f(u1.x), v5 = b2f(u1.y), v6 = b2f(u1.z), v7 = b2f(u1.w);
        s[0] += v0; q[0] += v0 * v0;  s[1] += v1; q[1] += v1 * v1;
        s[2] += v2; q[2] += v2 * v2;  s[3] += v3; q[3] += v3 * v3;
        s[4] += v4; q[4] += v4 * v4;  s[5] += v5; q[5] += v5 * v5;
        s[6] += v6; q[6] += v6 * v6;  s[7] += v7; q[7] += v7 * v7;
    }
#pragma unroll
    for (int j = 0; j < 8; ++j) { lsum[g][c0 + j] = s[j]; lsq[g][c0 + j] = q[j]; }
    __syncthreads();
    float ts = 0.f, tq = 0.f;
#pragma unroll
    for (int gg = 0; gg < 8; ++gg) { ts += lsum[gg][t]; tq += lsq[gg][t]; }
    int slot = b & (BN_SLOTS - 1);
    atomicAdd(&gsum[slot * HDIM + t], ts);
    atomicAdd(&gsq[slot * HDIM + t], tq);
}

// stage 2: fold 16 slots -> mu, inv; zero slots for next layer (graph-safe)
__global__ __launch_bounds__(256)
void bn_stats2_kernel(float* __restrict__ gsum, float* __restrict__ gsq,
                      float* __restrict__ mu, float* __restrict__ inv) {
    int c = threadIdx.x;
    float s = 0.f, s2 = 0.f;
#pragma unroll
    for (int b = 0; b < BN_SLOTS; ++b) {
        s += gsum[b * HDIM + c];
        s2 += gsq[b * HDIM + c];
        gsum[b * HDIM + c] = 0.f;
        gsq[b * HDIM + c] = 0.f;
    }
    float m = s / (float)N_NODES;
    float var = s2 / (float)N_NODES - m * m;
    mu[c] = m;
    inv[c] = rsqrtf(var + 1e-5f);
}

__global__ __launch_bounds__(256)
void bn_apply_kernel(const u16* __restrict__ outb, const float* __restrict__ mu,
                     const float* __restrict__ inv, const float* __restrict__ gamma_l,
                     const float* __restrict__ beta_l, u16* __restrict__ h, int addres) {
    int idx = blockIdx.x * 256 + threadIdx.x;       // N*H/4 threads
    int c = (idx & 63) << 2;
    ushort4 v4 = *(const ushort4*)(outb + (size_t)idx * 4);
    float4 m4 = *(const float4*)(mu + c);
    float4 i4 = *(const float4*)(inv + c);
    float4 g4 = *(const float4*)(gamma_l + c);
    float4 b4 = *(const float4*)(beta_l + c);
    float v0 = fmaxf(g4.x * (b2f(v4.x) - m4.x) * i4.x + b4.x, 0.f);
    float v1 = fmaxf(g4.y * (b2f(v4.y) - m4.y) * i4.y + b4.y, 0.f);
    float v2 = fmaxf(g4.z * (b2f(v4.z) - m4.z) * i4.z + b4.z, 0.f);
    float v3 = fmaxf(g4.w * (b2f(v4.w) - m4.w) * i4.w + b4.w, 0.f);
    if (addres) {
        ushort4 h4 = *(const ushort4*)(h + (size_t)idx * 4);
        v0 += b2f(h4.x); v1 += b2f(h4.y); v2 += b2f(h4.z); v3 += b2f(h4.w);
    }
    ushort4 o4;
    o4.x = f2bf(v0); o4.y = f2bf(v1); o4.z = f2bf(v2); o4.w = f2bf(v3);
    *(ushort4*)(h + (size_t)idx * 4) = o4;
}

// ---------------------------------------------------------------------------
// MFMA MHA: one 64-thread block per (graph, head); Q/K/V in separate buffers
// (row stride 256). Verified in rounds 12/13.
// ---------------------------------------------------------------------------
__global__ __launch_bounds__(64)
void mha_attn_kernel(const u16* __restrict__ Qb, const u16* __restrict__ Kb,
                     const u16* __restrict__ Vb, u16* __restrict__ o) {
    const int g = blockIdx.x >> 3;
    const int head = blockIdx.x & 7;
    const int l = threadIdx.x;
    __shared__ u16 VT[DHEAD][132];     // V^T: [d][key], keys zero-padded to 128
    __shared__ u16 P[16][132];         // row-tile of probabilities (bf16)
    const size_t base = (size_t)g * NPGRAPH * HDIM + head * 32;

    for (int idx = l; idx < 32 * 128; idx += 64) {
        int m = idx >> 5, d = idx & 31;
        u16 v = 0;
        if (m < 100) v = Vb[base + (size_t)m * HDIM + d];
        VT[d][m] = v;
    }
    bf16x8 kf[7];
#pragma unroll
    for (int n = 0; n < 7; ++n) {
        int r = n * 16 + (l & 15);
        kf[n] = *(const bf16x8*)(Kb + base + (size_t)r * HDIM + ((l >> 4) << 3));
    }
    __syncthreads();
    bf16x8 vf[2][4];
#pragma unroll
    for (int dt = 0; dt < 2; ++dt)
#pragma unroll
        for (int kc = 0; kc < 4; ++kc)
            vf[dt][kc] = *(const bf16x8*)(&VT[dt * 16 + (l & 15)][kc * 32 + ((l >> 4) << 3)]);

    const float SC = 0.17677669529663687f;   // 1/sqrt(32)
    const bool c6ok = (96 + (l & 15)) < 100;

    for (int mt = 0; mt < 7; ++mt) {
        int qr = mt * 16 + (l & 15);
        bf16x8 qf = *(const bf16x8*)(Qb + base + (size_t)qr * HDIM + ((l >> 4) << 3));
        f32x4 sa[7];
#pragma unroll
        for (int n = 0; n < 7; ++n) {
            f32x4 z = {0.f, 0.f, 0.f, 0.f};
            sa[n] = __builtin_amdgcn_mfma_f32_16x16x32_bf16(qf, kf[n], z, 0, 0, 0);
        }
        float linv[4];
#pragma unroll
        for (int j = 0; j < 4; ++j) {
            float m = -1e30f;
#pragma unroll
            for (int n = 0; n < 6; ++n) m = fmaxf(m, sa[n][j]);
            if (c6ok) m = fmaxf(m, sa[6][j]);
            m *= SC;
#pragma unroll
            for (int off = 1; off < 16; off <<= 1) m = fmaxf(m, __shfl_xor(m, off));
            float ls = 0.f;
            float pv[7];
#pragma unroll
            for (int n = 0; n < 7; ++n) {
                float p_ = 0.f;
                if (n < 6 || c6ok) p_ = __expf(SC * sa[n][j] - m);
                pv[n] = p_;
                ls += p_;
            }
#pragma unroll
            for (int off = 1; off < 16; off <<= 1) ls += __shfl_xor(ls, off);
            linv[j] = 1.f / ls;
            int rt = ((l >> 4) << 2) + j;
#pragma unroll
            for (int n = 0; n < 7; ++n) P[rt][n * 16 + (l & 15)] = f2bf(pv[n]);
            P[rt][112 + (l & 15)] = 0;
        }
        __syncthreads();
        f32x4 oa[2] = {};
#pragma unroll
        for (int kc = 0; kc < 4; ++kc) {
            bf16x8 pf = *(const bf16x8*)(&P[l & 15][kc * 32 + ((l >> 4) << 3)]);
            oa[0] = __builtin_amdgcn_mfma_f32_16x16x32_bf16(pf, vf[0][kc], oa[0], 0, 0, 0);
            oa[1] = __builtin_amdgcn_mfma_f32_16x16x32_bf16(pf, vf[1][kc], oa[1], 0, 0, 0);
        }
        int r0 = mt * 16 + ((l >> 4) << 2);
#pragma unroll
        for (int dt = 0; dt < 2; ++dt)
#pragma unroll
            for (int j = 0; j < 4; ++j) {
                int r = r0 + j;
                if (r < 100)
                    o[(size_t)(g * NPGRAPH + r) * HDIM + head * 32 + dt * 16 + (l & 15)] =
                        f2bf(oa[dt][j] * linv[j]);
            }
        __syncthreads();
    }
}

// mean pool over nodes per graph
__global__ __launch_bounds__(256)
void pool_kernel(const u16* __restrict__ o2, u16* __restrict__ pooled) {
    int g = blockIdx.x;
    int c = threadIdx.x;
    float s = 0.f;
    for (int r = 0; r < NPGRAPH; ++r) s += b2f(o2[((size_t)g * NPGRAPH + r) * HDIM + c]);
    pooled[g * HDIM + c] = f2bf(s * 0.01f);
}

// task heads
__global__ __launch_bounds__(64)
void heads_kernel(const u16* __restrict__ s2, const float* __restrict__ w1,
                  const float* __restrict__ b1, const float* __restrict__ w2,
                  const float* __restrict__ b2, float* __restrict__ out) {
    int g = blockIdx.x / TASKS;
    int tt = blockIdx.x % TASKS;
    int d = threadIdx.x;   // 64
    float s = b1[tt * 64 + d];
    const u16* srow = s2 + (size_t)g * 128;
    const float* wcol = w1 + (size_t)tt * 128 * 64 + d;
    for (int k = 0; k < 128; ++k) s += b2f(srow[k]) * wcol[k * 64];
    s = fmaxf(s, 0.f);
    float v = s * w2[tt * 64 + d];
#pragma unroll
    for (int off = 32; off >= 1; off >>= 1) v += __shfl_down(v, off);
    if (d == 0) out[g * TASKS + tt] = v + b2[tt];
}

// ---------------------------------------------------------------------------
extern "C" void kernel_launch(void* const* d_in, const int* in_sizes, int n_in,
                              void* d_out, int out_size, void* d_ws, size_t ws_size,
                              hipStream_t stream) {
    const float* x          = (const float*)d_in[0];
    const float* edge_attr  = (const float*)d_in[1];
    const int*   edge_index = (const int*)d_in[2];
    const float* atom_w     = (const float*)d_in[4];
    const float* atom_b     = (const float*)d_in[5];
    const float* edge_w     = (const float*)d_in[6];
    const float* edge_b     = (const float*)d_in[7];
    const float* gat_lin_w  = (const float*)d_in[8];
    const float* gat_lin_ew = (const float*)d_in[9];
    const float* att_src    = (const float*)d_in[10];
    const float* att_dst    = (const float*)d_in[11];
    const float* att_edge   = (const float*)d_in[12];
    const float* gat_bias   = (const float*)d_in[13];
    const float* bn_gamma   = (const float*)d_in[14];
    const float* bn_beta    = (const float*)d_in[15];
    const float* mha_in_w   = (const float*)d_in[16];
    const float* mha_in_b   = (const float*)d_in[17];
    const float* mha_out_w  = (const float*)d_in[18];
    const float* mha_out_b  = (const float*)d_in[19];
    const float* sh_w1      = (const float*)d_in[20];
    const float* sh_b1      = (const float*)d_in[21];
    const float* sh_w2      = (const float*)d_in[22];
    const float* sh_b2      = (const float*)d_in[23];
    const float* head_w1    = (const float*)d_in[24];
    const float* head_b1    = (const float*)d_in[25];
    const float* head_w2    = (const float*)d_in[26];
    const float* head_b2    = (const float*)d_in[27];
    float* out = (float*)d_out;

    const int* src = edge_index;
    const int* dst = edge_index + N_EDGES;

    // ---- workspace layout (bytes, 256B aligned; ~112 MB) ----
    size_t off = 0;
    auto alloc = [&](size_t bytes) -> void* {
        void* p = (char*)d_ws + off;
        off += (bytes + 255) & ~(size_t)255;
        return p;
    };
    const size_t NHB = (size_t)N_NODES * HDIM * sizeof(u16);      // 26,214,400
    u16* h_buf = (u16*)alloc(NHB);
    char* region1 = (char*)alloc((size_t)N_NODES * 768 * sizeof(u16));   // 78.6MB
    u16* xs_buf  = (u16*)region1;
    u16* out_buf = (u16*)(region1 + NHB);
    u16* a_e_all = (u16*)(region1 + 2 * NHB);
    u16* qkv3    = (u16*)region1;     // phase2: [3][N][256]; xs/outb/a_e dead
    u16* o2_buf  = (u16*)region1;     // phase3: qkv dead after attention
    u16* o_buf   = h_buf;             // h dead after qkv GEMM
    u16* x_bf    = out_buf;           // alias: dead before aggregate
    float* a_src_b = (float*)alloc((size_t)N_NODES * 8 * sizeof(float));
    float* a_dst_b = (float*)alloc((size_t)N_NODES * 8 * sizeof(float));
    float* gsum    = (float*)alloc(BN_SLOTS * HDIM * sizeof(float));
    float* gsq     = (float*)alloc(BN_SLOTS * HDIM * sizeof(float));
    float* mu_b    = (float*)alloc(HDIM * sizeof(float));
    float* inv_b   = (float*)alloc(HDIM * sizeof(float));
    float* P_e     = (float*)alloc(LAYERS * HDIM * 8 * sizeof(float));
    float* Qm      = (float*)alloc(256 * sizeof(float));
    float* c0m     = (float*)alloc(32 * sizeof(float));
    u16* atom_wt   = (u16*)alloc((size_t)HDIM * FATOM * sizeof(u16));
    u16* lin_wt    = (u16*)alloc((size_t)LAYERS * HDIM * HDIM * sizeof(u16));
    u16* in_w_bf   = (u16*)alloc((size_t)768 * HDIM * sizeof(u16));
    u16* out_w_bf  = (u16*)alloc((size_t)HDIM * HDIM * sizeof(u16));
    u16* sh1_t     = (u16*)alloc((size_t)HDIM * HDIM * sizeof(u16));
    u16* sh2_t     = (u16*)alloc((size_t)128 * HDIM * sizeof(u16));
    u16* pooled    = (u16*)alloc((size_t)GRAPHS * HDIM * sizeof(u16));
    u16* s1_b      = (u16*)alloc((size_t)GRAPHS * HDIM * sizeof(u16));
    u16* s2_b      = (u16*)alloc((size_t)GRAPHS * 128 * sizeof(u16));
    int* deg       = (int*)alloc(N_NODES * sizeof(int));
    int* row_ptr   = (int*)alloc((N_NODES + 256) * sizeof(int));
    int* cursor    = (int*)alloc(N_NODES * sizeof(int));
    int* col_src   = (int*)alloc(NFULL * sizeof(int));
    int* col_eid   = (int*)alloc(NFULL * sizeof(int));
    int* bsum      = (int*)alloc(64 * sizeof(int));
    (void)ws_size; (void)in_sizes; (void)n_in; (void)out_size;

    // ---- weight + input bf16 conversion ----
    convert_t_kernel<<<(HDIM * FATOM + 255) / 256, 256, 0, stream>>>(atom_w, atom_wt, FATOM, HDIM);
    convert_t4_kernel<<<(LAYERS * HDIM * HDIM) / 256, 256, 0, stream>>>(gat_lin_w, lin_wt);
    convert_kernel<<<(768 * HDIM + 255) / 256, 256, 0, stream>>>(mha_in_w, in_w_bf, 768 * HDIM);
    convert_kernel<<<(HDIM * HDIM + 255) / 256, 256, 0, stream>>>(mha_out_w, out_w_bf, HDIM * HDIM);
    convert_t_kernel<<<(HDIM * HDIM + 255) / 256, 256, 0, stream>>>(sh_w1, sh1_t, HDIM, HDIM);
    convert_t_kernel<<<(HDIM * 128 + 255) / 256, 256, 0, stream>>>(sh_w2, sh2_t, HDIM, 128);
    convert_kernel<<<(N_NODES * FATOM + 255) / 256, 256, 0, stream>>>(x, x_bf, N_NODES * FATOM);

    // ---- CSR (3-stage scan) ----
    hipMemsetAsync(deg, 0, N_NODES * sizeof(int), stream);
    edge_hist_kernel<<<(N_EDGES + 255) / 256, 256, 0, stream>>>(dst, deg);
    scan1_kernel<<<SCAN_BLOCKS, 1024, 0, stream>>>(deg, row_ptr, bsum);
    scan2_kernel<<<1, 64, 0, stream>>>(bsum, row_ptr);
    scan3_kernel<<<N_NODES / 256, 256, 0, stream>>>(row_ptr, bsum);
    selfloop_init_kernel<<<(N_NODES + 255) / 256, 256, 0, stream>>>(row_ptr, cursor, col_src, col_eid);
    scatter_kernel<<<(N_EDGES + 255) / 256, 256, 0, stream>>>(src, dst, cursor, col_src, col_eid);

    // ---- attention-logit edge projections ----
    proj_pe_kernel<<<32, 256, 0, stream>>>(gat_lin_ew, att_edge, P_e);
    proj_q_kernel<<<1, 256, 0, stream>>>(edge_w, edge_b, P_e, Qm, c0m);
    ae_real_kernel<<<N_EDGES / 8, 256, 0, stream>>>(edge_attr, Qm, c0m, a_e_all);
    ae_self_kernel<<<N_NODES / 8, 256, 0, stream>>>(
        edge_attr, row_ptr, col_eid, Qm, c0m, a_e_all);

    // ---- atom encoder ----
    gemm_mfma_kernel<true, false, false><<<(HDIM / 128) * (N_NODES / 128), 256, 0, stream>>>(
        x_bf, atom_wt, atom_b, h_buf, N_NODES, FATOM, HDIM);

    // ---- GAT layers ----
    hipMemsetAsync(gsum, 0, BN_SLOTS * HDIM * sizeof(float), stream);
    hipMemsetAsync(gsq, 0, BN_SLOTS * HDIM * sizeof(float), stream);
    for (int li = 0; li < LAYERS; ++li) {
        gemm_mfma_kernel<false, false, false><<<(HDIM / 128) * (N_NODES / 128), 256, 0, stream>>>(
            h_buf, lin_wt + (size_t)li * HDIM * HDIM, nullptr, xs_buf, N_NODES, HDIM, HDIM);
        gat_asd_kernel<<<N_NODES / 4, 256, 0, stream>>>(
            xs_buf, att_src + li * HDIM, att_dst + li * HDIM, a_src_b, a_dst_b);
        gat_aggregate_kernel<<<N_NODES / 4, 256, 0, stream>>>(
            xs_buf, a_src_b, a_dst_b, a_e_all, row_ptr, col_src, col_eid,
            gat_bias + li * HDIM, out_buf, li);
        bn_stats1_kernel<<<N_NODES / 64, 256, 0, stream>>>(out_buf, gsum, gsq);
        bn_stats2_kernel<<<1, 256, 0, stream>>>(gsum, gsq, mu_b, inv_b);
        bn_apply_kernel<<<(N_NODES * HDIM / 4) / 256, 256, 0, stream>>>(
            out_buf, mu_b, inv_b, bn_gamma + li * HDIM, bn_beta + li * HDIM, h_buf, li > 0 ? 1 : 0);
    }

    // ---- MHA: single qkv GEMM, epilogue routed into [3][N][256] buffers ----
    gemm_mfma_kernel<true, false, true><<<(768 / 128) * (N_NODES / 128), 256, 0, stream>>>(
        h_buf, in_w_bf, mha_in_b, qkv3, N_NODES, HDIM, 768);
    mha_attn_kernel<<<GRAPHS * NHEADS, 64, 0, stream>>>(
        qkv3, qkv3 + (size_t)N_NODES * 256, qkv3 + (size_t)2 * N_NODES * 256, o_buf);
    gemm_mfma_kernel<true, false, false><<<(HDIM / 128) * (N_NODES / 128), 256, 0, stream>>>(
        o_buf, out_w_bf, mha_out_b, o2_buf, N_NODES, HDIM, HDIM);
    pool_kernel<<<GRAPHS, 256, 0, stream>>>(o2_buf, pooled);

    // ---- shared MLP + task heads ----
    gemm_mfma_kernel<true, true, false><<<(HDIM / 128) * (GRAPHS / 128), 256, 0, stream>>>(
        pooled, sh1_t, sh_b1, s1_b, GRAPHS, HDIM, HDIM);
    gemm_mfma_kernel<true, true, false><<<(128 / 128) * (GRAPHS / 128), 256, 0, stream>>>(
        s1_b, sh2_t, sh_b2, s2_b, GRAPHS, HDIM, 128);
    heads_kernel<<<GRAPHS * TASKS, 64, 0, stream>>>(
        s2_b, head_w1, head_b1, head_w2, head_b2, out);
}